// Round 6
// baseline (1051.998 us; speedup 1.0000x reference)
//
#include <hip/hip_runtime.h>

#define N_P 50000
#define N_HE 5000
#define N_E 800000
#define D_IN 128
#define D_HID 256
#define N_HEADS 4
#define HEAD_DIM 64
#define PT 8        // proteins per block in k_final
#define PTP 9       // padded LDS stride (odd -> conflict-free transposes)
#define CAP_HE 320  // bucket capacity per hyperedge (mean 160)
#define CAP_P  64   // bucket capacity per protein   (mean 16)

// ---------------- zero the counters (ints) ----------------
__global__ void k_zero_int(int* __restrict__ p, unsigned n) {
    unsigned i = blockIdx.x * blockDim.x + threadIdx.x;
    unsigned stride = gridDim.x * blockDim.x;
    for (; i < n; i += stride) p[i] = 0;
}

// ---------------- bucket edges by hid and by pid ----------------
__global__ void k_bucket(
    const int* __restrict__ edge_pid, const int* __restrict__ edge_hid,
    int* __restrict__ cnt_he, int* __restrict__ cnt_p,
    int* __restrict__ list_he, int* __restrict__ list_p,
    int* __restrict__ ovf_he, int* __restrict__ ovf_he_cnt,
    int* __restrict__ ovf_p,  int* __restrict__ ovf_p_cnt) {
    unsigned e = blockIdx.x * blockDim.x + threadIdx.x;
    unsigned stride = gridDim.x * blockDim.x;
    for (; e < N_E; e += stride) {
        int h = edge_hid[e], p = edge_pid[e];
        int pos = atomicAdd(cnt_he + h, 1);
        if (pos < CAP_HE) list_he[h * CAP_HE + pos] = (int)e;
        else              ovf_he[atomicAdd(ovf_he_cnt, 1)] = (int)e;
        int pp = atomicAdd(cnt_p + p, 1);
        if (pp < CAP_P)   list_p[p * CAP_P + pp] = (int)e;
        else              ovf_p[atomicAdd(ovf_p_cnt, 1)] = (int)e;
    }
}

// ---------------- Stage 1 gather: he_feat[h] = sum feat[pid]*w ----------------
__global__ void k_gather_he(
    const float* __restrict__ feat, const float* __restrict__ edge_w,
    const int* __restrict__ edge_pid,
    const int* __restrict__ cnt_he, const int* __restrict__ list_he,
    float* __restrict__ he_feat) {
    __shared__ float tmp[D_IN];
    int h = blockIdx.x;                 // 5000 blocks
    int n = cnt_he[h]; if (n > CAP_HE) n = CAP_HE;
    const int* lst = list_he + h * CAP_HE;
    int t = threadIdx.x;                // 256 = 2 halves x 128 dims
    int half = t >> 7, d = t & 127;
    float acc = 0.f;
    for (int k = half; k < n; k += 2) {
        int e = lst[k];
        acc += feat[(unsigned)edge_pid[e] * D_IN + d] * edge_w[e];
    }
    if (half == 1) tmp[d] = acc;
    __syncthreads();
    if (half == 0) he_feat[h * D_IN + d] = acc + tmp[d];
}

// overflow fallback (normally empty)
__global__ void k_ovf_he(
    const float* __restrict__ feat, const float* __restrict__ edge_w,
    const int* __restrict__ edge_pid, const int* __restrict__ edge_hid,
    const int* __restrict__ ovf, const int* __restrict__ ovf_cnt,
    float* __restrict__ he_feat) {
    unsigned n = (unsigned)(*ovf_cnt) * D_IN;
    unsigned i = blockIdx.x * blockDim.x + threadIdx.x;
    unsigned stride = gridDim.x * blockDim.x;
    for (; i < n; i += stride) {
        int e = ovf[i >> 7];
        unsigned d = i & 127u;
        atomicAdd(he_feat + (unsigned)edge_hid[e] * D_IN + d,
                  feat[(unsigned)edge_pid[e] * D_IN + d] * edge_w[e]);
    }
}

// ---------------- Stage 2: attention; he_feat row scaled IN PLACE ----------------
__global__ void k_attn(
    float* __restrict__ he_feat,
    const float* __restrict__ Wh1, const float* __restrict__ bh1,
    const float* __restrict__ Wh2, const float* __restrict__ bh2,
    const float* __restrict__ Wfuse) {
    __shared__ float hef[D_IN];
    __shared__ float attnv[N_HEADS];
    __shared__ float heattn;
    int t = threadIdx.x;      // 256 threads = 4 waves; wave == head
    int head = t >> 6;
    int k = t & 63;
    for (int n = blockIdx.x; n < N_HE; n += gridDim.x) {
        if (t < D_IN) hef[t] = he_feat[n * D_IN + t];
        __syncthreads();
        float s = bh1[head * HEAD_DIM + k];
        for (int d = 0; d < D_IN; ++d)
            s += hef[d] * Wh1[(head * D_IN + d) * HEAD_DIM + k];
        s = fmaxf(s, 0.f);
        float val = s * Wh2[head * HEAD_DIM + k];
        for (int off = 32; off; off >>= 1) val += __shfl_down(val, off);
        if (k == 0) {
            float x = val + bh2[head];
            attnv[head] = 1.f / (1.f + expf(-x));
        }
        __syncthreads();
        if (t == 0) {
            float ha = 0.f;
            for (int h = 0; h < N_HEADS; ++h) ha += attnv[h] * Wfuse[h];
            heattn = ha;
        }
        __syncthreads();
        if (t < D_IN) he_feat[n * D_IN + t] = hef[t] * heattn;
        __syncthreads();
    }
}

// ---------------- Stage 4: fused cluster-gather + register-blocked MLP ----------------
__global__ void k_final(
    const float* __restrict__ feat, const float* __restrict__ he_weighted,
    const float* __restrict__ edge_w,
    const int* __restrict__ edge_pid, const int* __restrict__ edge_hid,
    const int* __restrict__ cnt_p, const int* __restrict__ list_p,
    const int* __restrict__ ovf_p, const int* __restrict__ ovf_p_cnt,
    const float* __restrict__ Wself, const float* __restrict__ bself,
    const float* __restrict__ Wclu, const float* __restrict__ bclu,
    const float* __restrict__ Wf1, const float* __restrict__ bf1,
    const float* __restrict__ Wf2, const float* __restrict__ bf2,
    const float* __restrict__ Wf3, const float* __restrict__ bf3,
    float* __restrict__ out) {
    __shared__ float featT[D_IN * PTP];        // [d][p], stride 9
    __shared__ float cluT [D_IN * PTP];
    __shared__ float catT [2 * D_IN * PTP];
    __shared__ float h1T  [D_HID * PTP];
    __shared__ float h2T  [(D_HID / 2) * PTP];
    __shared__ float fw   [PT * 2];
    int t = threadIdx.x;

    for (int pb = blockIdx.x; pb < N_P / PT; pb += gridDim.x) {
        int p0 = pb * PT;
        const float* fbase = feat + (size_t)p0 * D_IN;

        // ---- load + transpose feat rows ----
        #pragma unroll
        for (int k = 0; k < (PT * D_IN) / 256; ++k) {
            int i = t + k * 256;
            int p = i >> 7, d = i & 127;
            featT[d * PTP + p] = fbase[i];
        }

        // ---- fused cluster gather: cluT[d][pl] = sum_e he_w[hid]*w ----
        {
            int pg = t >> 7, d = t & 127;     // two 128-thread groups
            int oc = *ovf_p_cnt;
            #pragma unroll
            for (int pp = 0; pp < PT / 2; ++pp) {
                int pl = pp * 2 + pg;
                int p = p0 + pl;
                int n = cnt_p[p]; if (n > CAP_P) n = CAP_P;
                const int* lst = list_p + (size_t)p * CAP_P;
                float acc = 0.f;
                for (int k = 0; k < n; ++k) {
                    int e = lst[k];
                    acc += he_weighted[(unsigned)edge_hid[e] * D_IN + d] * edge_w[e];
                }
                for (int k = 0; k < oc; ++k) {   // overflow (normally oc==0)
                    int e = ovf_p[k];
                    if (edge_pid[e] == p)
                        acc += he_weighted[(unsigned)edge_hid[e] * D_IN + d] * edge_w[e];
                }
                cluT[d * PTP + pl] = acc;
            }
        }
        __syncthreads();

        // ---- cat = [feat@Wself+bself | clu@Wclu+bclu], unroll d by 8 ----
        {
            int j = t;
            const float* W;  const float* act;  float b;  int jj;
            if (j < D_IN) { W = Wself; b = bself[j];        act = featT; jj = j; }
            else          { W = Wclu;  b = bclu[j - D_IN];  act = cluT;  jj = j - D_IN; }
            float acc[PT];
            #pragma unroll
            for (int p = 0; p < PT; ++p) acc[p] = b;
            for (int d0 = 0; d0 < D_IN; d0 += 8) {
                float w[8];
                #pragma unroll
                for (int q = 0; q < 8; ++q) w[q] = W[(d0 + q) * D_IN + jj];
                #pragma unroll
                for (int q = 0; q < 8; ++q)
                    #pragma unroll
                    for (int p = 0; p < PT; ++p)
                        acc[p] += act[(d0 + q) * PTP + p] * w[q];
            }
            #pragma unroll
            for (int p = 0; p < PT; ++p) catT[j * PTP + p] = acc[p];
        }
        __syncthreads();

        // ---- h1 = relu(cat @ Wf1 + bf1), unroll d by 8 ----
        {
            int j = t;
            float acc[PT];
            float b = bf1[j];
            #pragma unroll
            for (int p = 0; p < PT; ++p) acc[p] = b;
            for (int d0 = 0; d0 < 2 * D_IN; d0 += 8) {
                float w[8];
                #pragma unroll
                for (int q = 0; q < 8; ++q) w[q] = Wf1[(d0 + q) * D_HID + j];
                #pragma unroll
                for (int q = 0; q < 8; ++q)
                    #pragma unroll
                    for (int p = 0; p < PT; ++p)
                        acc[p] += catT[(d0 + q) * PTP + p] * w[q];
            }
            #pragma unroll
            for (int p = 0; p < PT; ++p) h1T[j * PTP + p] = fmaxf(acc[p], 0.f);
        }
        __syncthreads();

        // ---- h2 = relu(h1 @ Wf2 + bf2), 4 proteins per thread, unroll d by 8 ----
        {
            int j = t & 127, ph = t >> 7;
            float acc[4];
            float b = bf2[j];
            #pragma unroll
            for (int q = 0; q < 4; ++q) acc[q] = b;
            for (int d0 = 0; d0 < D_HID; d0 += 8) {
                float w[8];
                #pragma unroll
                for (int q = 0; q < 8; ++q) w[q] = Wf2[(d0 + q) * (D_HID / 2) + j];
                #pragma unroll
                for (int q = 0; q < 8; ++q)
                    #pragma unroll
                    for (int r = 0; r < 4; ++r)
                        acc[r] += h1T[(d0 + q) * PTP + ph * 4 + r] * w[q];
            }
            #pragma unroll
            for (int q = 0; q < 4; ++q) h2T[j * PTP + ph * 4 + q] = fmaxf(acc[q], 0.f);
        }
        __syncthreads();

        // ---- logits + softmax (32 threads per protein) ----
        {
            int p = t >> 5, k = t & 31;
            float s0 = 0.f, s1 = 0.f;
            for (int d = k; d < D_HID / 2; d += 32) {
                float h = h2T[d * PTP + p];
                s0 += h * Wf3[d * 2 + 0];
                s1 += h * Wf3[d * 2 + 1];
            }
            for (int off = 16; off; off >>= 1) {
                s0 += __shfl_down(s0, off, 32);
                s1 += __shfl_down(s1, off, 32);
            }
            if (k == 0) {
                float l0 = s0 + bf3[0], l1 = s1 + bf3[1];
                float m = fmaxf(l0, l1);
                float e0 = expf(l0 - m), e1 = expf(l1 - m);
                float inv = 1.f / (e0 + e1);
                fw[p * 2 + 0] = e0 * inv;
                fw[p * 2 + 1] = e1 * inv;
            }
        }
        __syncthreads();

        // ---- fuse + residual + relu + store ----
        #pragma unroll
        for (int k = 0; k < (PT * D_IN) / 256; ++k) {
            int i = t + k * 256;
            int p = i >> 7, j = i & 127;
            float fused = catT[j * PTP + p] * fw[p * 2 + 0] +
                          catT[(D_IN + j) * PTP + p] * fw[p * 2 + 1];
            float v = fused + featT[j * PTP + p];
            out[(size_t)p0 * D_IN + i] = fmaxf(v, 0.f);
        }
        __syncthreads();
    }
}

extern "C" void kernel_launch(void* const* d_in, const int* in_sizes, int n_in,
                              void* d_out, int out_size, void* d_ws, size_t ws_size,
                              hipStream_t stream) {
    (void)in_sizes; (void)n_in; (void)out_size; (void)ws_size;
    const float* feat   = (const float*)d_in[0];
    const float* edge_w = (const float*)d_in[1];
    const float* Wself  = (const float*)d_in[2];
    const float* bself  = (const float*)d_in[3];
    const float* Wclu   = (const float*)d_in[4];
    const float* bclu   = (const float*)d_in[5];
    const float* Wh1    = (const float*)d_in[6];
    const float* bh1    = (const float*)d_in[7];
    const float* Wh2    = (const float*)d_in[8];
    const float* bh2    = (const float*)d_in[9];
    const float* Wfuse  = (const float*)d_in[10];
    const float* Wf1    = (const float*)d_in[11];
    const float* bf1_   = (const float*)d_in[12];
    const float* Wf2    = (const float*)d_in[13];
    const float* bf2_   = (const float*)d_in[14];
    const float* Wf3    = (const float*)d_in[15];
    const float* bf3_   = (const float*)d_in[16];
    const int* edge_pid = (const int*)d_in[17];
    const int* edge_hid = (const int*)d_in[18];
    float* out = (float*)d_out;

    // ---- workspace carve-up ----
    float* he_feat = (float*)d_ws;                    // 5000*128 (weighted in place)
    int* ibase   = (int*)(he_feat + (size_t)N_HE * D_IN);
    int* cnt_he  = ibase;                             // 5000
    int* cnt_p   = cnt_he + N_HE;                     // 50000
    int* ovf_he_cnt = cnt_p + N_P;                    // 1
    int* ovf_p_cnt  = ovf_he_cnt + 1;                 // 1
    int* list_he = ovf_p_cnt + 1;                     // 5000*CAP_HE
    int* list_p  = list_he + (size_t)N_HE * CAP_HE;   // 50000*CAP_P
    int* ovf_he  = list_p + (size_t)N_P * CAP_P;      // N_E
    int* ovf_p   = ovf_he + N_E;                      // N_E

    k_zero_int<<<64, 256, 0, stream>>>(cnt_he, (unsigned)(N_HE + N_P + 2));
    k_bucket<<<2048, 256, 0, stream>>>(edge_pid, edge_hid, cnt_he, cnt_p,
                                       list_he, list_p, ovf_he, ovf_he_cnt, ovf_p, ovf_p_cnt);
    k_gather_he<<<N_HE, 256, 0, stream>>>(feat, edge_w, edge_pid, cnt_he, list_he, he_feat);
    k_ovf_he<<<256, 256, 0, stream>>>(feat, edge_w, edge_pid, edge_hid, ovf_he, ovf_he_cnt, he_feat);
    k_attn<<<2048, 256, 0, stream>>>(he_feat, Wh1, bh1, Wh2, bh2, Wfuse);
    k_final<<<N_P / PT, 256, 0, stream>>>(feat, he_feat, edge_w, edge_pid, edge_hid,
                                          cnt_p, list_p, ovf_p, ovf_p_cnt,
                                          Wself, bself, Wclu, bclu,
                                          Wf1, bf1_, Wf2, bf2_, Wf3, bf3_, out);
}

// Round 7
// 673.778 us; speedup vs baseline: 1.5613x; 1.5613x over previous
//
#include <hip/hip_runtime.h>

#define N_P 50000
#define N_HE 5000
#define N_E 800000
#define D_IN 128
#define D_HID 256
#define N_HEADS 4
#define HEAD_DIM 64
#define PT 8        // proteins per block in k_final
#define PTP 9       // padded LDS stride (odd -> conflict-free transposes)
#define CAP_HE 320  // bucket capacity per hyperedge (mean 160)
#define CAP_P  64   // bucket capacity per protein   (mean 16)

// ---------------- zero the counters (ints) ----------------
__global__ void k_zero_int(int* __restrict__ p, unsigned n) {
    unsigned i = blockIdx.x * blockDim.x + threadIdx.x;
    unsigned stride = gridDim.x * blockDim.x;
    for (; i < n; i += stride) p[i] = 0;
}

// ---------------- bucket edges; lists store packed (index, weight) ----------------
__global__ void k_bucket(
    const int* __restrict__ edge_pid, const int* __restrict__ edge_hid,
    const float* __restrict__ edge_w,
    int* __restrict__ cnt_he, int* __restrict__ cnt_p,
    int2* __restrict__ list_he, int2* __restrict__ list_p,
    int* __restrict__ ovf_he, int* __restrict__ ovf_he_cnt,
    int* __restrict__ ovf_p,  int* __restrict__ ovf_p_cnt) {
    unsigned e = blockIdx.x * blockDim.x + threadIdx.x;
    unsigned stride = gridDim.x * blockDim.x;
    for (; e < N_E; e += stride) {
        int h = edge_hid[e], p = edge_pid[e];
        int wbits = __float_as_int(edge_w[e]);
        int pos = atomicAdd(cnt_he + h, 1);
        if (pos < CAP_HE) list_he[h * CAP_HE + pos] = make_int2(p, wbits);  // (pid, w)
        else              ovf_he[atomicAdd(ovf_he_cnt, 1)] = (int)e;
        int pp = atomicAdd(cnt_p + p, 1);
        if (pp < CAP_P)   list_p[p * CAP_P + pp] = make_int2(h, wbits);     // (hid, w)
        else              ovf_p[atomicAdd(ovf_p_cnt, 1)] = (int)e;
    }
}

// ---------------- Stage 1 gather: he_feat[h] = sum feat[pid]*w ----------------
__global__ void k_gather_he(
    const float* __restrict__ feat,
    const int* __restrict__ cnt_he, const int2* __restrict__ list_he,
    float* __restrict__ he_feat) {
    __shared__ float tmp[D_IN];
    int h = blockIdx.x;                 // 5000 blocks
    int n = cnt_he[h]; if (n > CAP_HE) n = CAP_HE;
    const int2* lst = list_he + (size_t)h * CAP_HE;
    int t = threadIdx.x;                // 256 = 2 halves x 128 dims
    int half = t >> 7, d = t & 127;
    float acc = 0.f;
    #pragma unroll 4
    for (int k = half; k < n; k += 2) {
        int2 pr = lst[k];               // broadcast read (same addr across group)
        acc += feat[(unsigned)pr.x * D_IN + d] * __int_as_float(pr.y);
    }
    if (half == 1) tmp[d] = acc;
    __syncthreads();
    if (half == 0) he_feat[h * D_IN + d] = acc + tmp[d];
}

// overflow fallback (normally empty)
__global__ void k_ovf_he(
    const float* __restrict__ feat, const float* __restrict__ edge_w,
    const int* __restrict__ edge_pid, const int* __restrict__ edge_hid,
    const int* __restrict__ ovf, const int* __restrict__ ovf_cnt,
    float* __restrict__ he_feat) {
    unsigned n = (unsigned)(*ovf_cnt) * D_IN;
    unsigned i = blockIdx.x * blockDim.x + threadIdx.x;
    unsigned stride = gridDim.x * blockDim.x;
    for (; i < n; i += stride) {
        int e = ovf[i >> 7];
        unsigned d = i & 127u;
        atomicAdd(he_feat + (unsigned)edge_hid[e] * D_IN + d,
                  feat[(unsigned)edge_pid[e] * D_IN + d] * edge_w[e]);
    }
}

// ---------------- Stage 2: attention; he_feat row scaled IN PLACE ----------------
__global__ void k_attn(
    float* __restrict__ he_feat,
    const float* __restrict__ Wh1, const float* __restrict__ bh1,
    const float* __restrict__ Wh2, const float* __restrict__ bh2,
    const float* __restrict__ Wfuse) {
    __shared__ float hef[D_IN];
    __shared__ float attnv[N_HEADS];
    __shared__ float heattn;
    int t = threadIdx.x;      // 256 threads = 4 waves; wave == head
    int head = t >> 6;
    int k = t & 63;
    for (int n = blockIdx.x; n < N_HE; n += gridDim.x) {
        if (t < D_IN) hef[t] = he_feat[n * D_IN + t];
        __syncthreads();
        float s = bh1[head * HEAD_DIM + k];
        for (int d = 0; d < D_IN; ++d)
            s += hef[d] * Wh1[(head * D_IN + d) * HEAD_DIM + k];
        s = fmaxf(s, 0.f);
        float val = s * Wh2[head * HEAD_DIM + k];
        for (int off = 32; off; off >>= 1) val += __shfl_down(val, off);
        if (k == 0) {
            float x = val + bh2[head];
            attnv[head] = 1.f / (1.f + expf(-x));
        }
        __syncthreads();
        if (t == 0) {
            float ha = 0.f;
            for (int h = 0; h < N_HEADS; ++h) ha += attnv[h] * Wfuse[h];
            heattn = ha;
        }
        __syncthreads();
        if (t < D_IN) he_feat[n * D_IN + t] = hef[t] * heattn;
        __syncthreads();
    }
}

// ---------------- Stage 3 gather: cluster_feat[p] = sum he_w[hid]*w ----------------
__global__ void k_gather_clu(
    const float* __restrict__ he_weighted,
    const int* __restrict__ cnt_p, const int2* __restrict__ list_p,
    float* __restrict__ cluster_feat) {
    int p = blockIdx.x;                 // 50000 blocks
    int n = cnt_p[p]; if (n > CAP_P) n = CAP_P;
    const int2* lst = list_p + (size_t)p * CAP_P;
    int d = threadIdx.x;                // 128 threads
    float acc = 0.f;
    #pragma unroll 4
    for (int k = 0; k < n; ++k) {
        int2 pr = lst[k];               // broadcast read
        acc += he_weighted[(unsigned)pr.x * D_IN + d] * __int_as_float(pr.y);
    }
    cluster_feat[p * D_IN + d] = acc;
}

// overflow fallback (normally empty)
__global__ void k_ovf_clu(
    const float* __restrict__ he_weighted, const float* __restrict__ edge_w,
    const int* __restrict__ edge_pid, const int* __restrict__ edge_hid,
    const int* __restrict__ ovf, const int* __restrict__ ovf_cnt,
    float* __restrict__ cluster_feat) {
    unsigned n = (unsigned)(*ovf_cnt) * D_IN;
    unsigned i = blockIdx.x * blockDim.x + threadIdx.x;
    unsigned stride = gridDim.x * blockDim.x;
    for (; i < n; i += stride) {
        int e = ovf[i >> 7];
        unsigned d = i & 127u;
        atomicAdd(cluster_feat + (unsigned)edge_pid[e] * D_IN + d,
                  he_weighted[(unsigned)edge_hid[e] * D_IN + d] * edge_w[e]);
    }
}

// ---------------- Stage 4: register-blocked fused MLP (unroll-8 weight loads) ----------------
__global__ void k_final(
    const float* __restrict__ feat, const float* __restrict__ cluster_feat,
    const float* __restrict__ Wself, const float* __restrict__ bself,
    const float* __restrict__ Wclu, const float* __restrict__ bclu,
    const float* __restrict__ Wf1, const float* __restrict__ bf1,
    const float* __restrict__ Wf2, const float* __restrict__ bf2,
    const float* __restrict__ Wf3, const float* __restrict__ bf3,
    float* __restrict__ out) {
    __shared__ float featT[D_IN * PTP];        // [d][p], stride 9
    __shared__ float cluT [D_IN * PTP];
    __shared__ float catT [2 * D_IN * PTP];
    __shared__ float h1T  [D_HID * PTP];
    __shared__ float h2T  [(D_HID / 2) * PTP];
    __shared__ float fw   [PT * 2];
    int t = threadIdx.x;

    for (int pb = blockIdx.x; pb < N_P / PT; pb += gridDim.x) {
        int p0 = pb * PT;
        const float* fbase = feat + (size_t)p0 * D_IN;
        const float* cbase = cluster_feat + (size_t)p0 * D_IN;

        #pragma unroll
        for (int k = 0; k < (PT * D_IN) / 256; ++k) {
            int i = t + k * 256;
            int p = i >> 7, d = i & 127;
            featT[d * PTP + p] = fbase[i];
            cluT [d * PTP + p] = cbase[i];
        }
        __syncthreads();

        {   // cat = [feat@Wself+bself | clu@Wclu+bclu], d unrolled by 8
            int j = t;
            const float* W;  const float* act;  float b;  int jj;
            if (j < D_IN) { W = Wself; b = bself[j];        act = featT; jj = j; }
            else          { W = Wclu;  b = bclu[j - D_IN];  act = cluT;  jj = j - D_IN; }
            float acc[PT];
            #pragma unroll
            for (int p = 0; p < PT; ++p) acc[p] = b;
            for (int d0 = 0; d0 < D_IN; d0 += 8) {
                float w[8];
                #pragma unroll
                for (int q = 0; q < 8; ++q) w[q] = W[(d0 + q) * D_IN + jj];
                #pragma unroll
                for (int q = 0; q < 8; ++q)
                    #pragma unroll
                    for (int p = 0; p < PT; ++p)
                        acc[p] += act[(d0 + q) * PTP + p] * w[q];
            }
            #pragma unroll
            for (int p = 0; p < PT; ++p) catT[j * PTP + p] = acc[p];
        }
        __syncthreads();

        {   // h1 = relu(cat @ Wf1 + bf1), d unrolled by 8
            int j = t;
            float acc[PT];
            float b = bf1[j];
            #pragma unroll
            for (int p = 0; p < PT; ++p) acc[p] = b;
            for (int d0 = 0; d0 < 2 * D_IN; d0 += 8) {
                float w[8];
                #pragma unroll
                for (int q = 0; q < 8; ++q) w[q] = Wf1[(d0 + q) * D_HID + j];
                #pragma unroll
                for (int q = 0; q < 8; ++q)
                    #pragma unroll
                    for (int p = 0; p < PT; ++p)
                        acc[p] += catT[(d0 + q) * PTP + p] * w[q];
            }
            #pragma unroll
            for (int p = 0; p < PT; ++p) h1T[j * PTP + p] = fmaxf(acc[p], 0.f);
        }
        __syncthreads();

        {   // h2 = relu(h1 @ Wf2 + bf2), 4 proteins/thread, d unrolled by 8
            int j = t & 127, ph = t >> 7;
            float acc[4];
            float b = bf2[j];
            #pragma unroll
            for (int q = 0; q < 4; ++q) acc[q] = b;
            for (int d0 = 0; d0 < D_HID; d0 += 8) {
                float w[8];
                #pragma unroll
                for (int q = 0; q < 8; ++q) w[q] = Wf2[(d0 + q) * (D_HID / 2) + j];
                #pragma unroll
                for (int q = 0; q < 8; ++q)
                    #pragma unroll
                    for (int r = 0; r < 4; ++r)
                        acc[r] += h1T[(d0 + q) * PTP + ph * 4 + r] * w[q];
            }
            #pragma unroll
            for (int q = 0; q < 4; ++q) h2T[j * PTP + ph * 4 + q] = fmaxf(acc[q], 0.f);
        }
        __syncthreads();

        {   // logits + softmax (32 threads per protein)
            int p = t >> 5, k = t & 31;
            float s0 = 0.f, s1 = 0.f;
            for (int d = k; d < D_HID / 2; d += 32) {
                float h = h2T[d * PTP + p];
                s0 += h * Wf3[d * 2 + 0];
                s1 += h * Wf3[d * 2 + 1];
            }
            for (int off = 16; off; off >>= 1) {
                s0 += __shfl_down(s0, off, 32);
                s1 += __shfl_down(s1, off, 32);
            }
            if (k == 0) {
                float l0 = s0 + bf3[0], l1 = s1 + bf3[1];
                float m = fmaxf(l0, l1);
                float e0 = expf(l0 - m), e1 = expf(l1 - m);
                float inv = 1.f / (e0 + e1);
                fw[p * 2 + 0] = e0 * inv;
                fw[p * 2 + 1] = e1 * inv;
            }
        }
        __syncthreads();

        #pragma unroll
        for (int k = 0; k < (PT * D_IN) / 256; ++k) {
            int i = t + k * 256;
            int p = i >> 7, j = i & 127;
            float fused = catT[j * PTP + p] * fw[p * 2 + 0] +
                          catT[(D_IN + j) * PTP + p] * fw[p * 2 + 1];
            float v = fused + featT[j * PTP + p];
            out[(size_t)p0 * D_IN + i] = fmaxf(v, 0.f);
        }
        __syncthreads();
    }
}

extern "C" void kernel_launch(void* const* d_in, const int* in_sizes, int n_in,
                              void* d_out, int out_size, void* d_ws, size_t ws_size,
                              hipStream_t stream) {
    (void)in_sizes; (void)n_in; (void)out_size; (void)ws_size;
    const float* feat   = (const float*)d_in[0];
    const float* edge_w = (const float*)d_in[1];
    const float* Wself  = (const float*)d_in[2];
    const float* bself  = (const float*)d_in[3];
    const float* Wclu   = (const float*)d_in[4];
    const float* bclu   = (const float*)d_in[5];
    const float* Wh1    = (const float*)d_in[6];
    const float* bh1    = (const float*)d_in[7];
    const float* Wh2    = (const float*)d_in[8];
    const float* bh2    = (const float*)d_in[9];
    const float* Wfuse  = (const float*)d_in[10];
    const float* Wf1    = (const float*)d_in[11];
    const float* bf1_   = (const float*)d_in[12];
    const float* Wf2    = (const float*)d_in[13];
    const float* bf2_   = (const float*)d_in[14];
    const float* Wf3    = (const float*)d_in[15];
    const float* bf3_   = (const float*)d_in[16];
    const int* edge_pid = (const int*)d_in[17];
    const int* edge_hid = (const int*)d_in[18];
    float* out = (float*)d_out;

    // ---- workspace carve-up (floats, then int2 lists, then ints) ----
    float* he_feat      = (float*)d_ws;                         // 5000*128 (weighted in place)
    float* cluster_feat = he_feat + (size_t)N_HE * D_IN;        // 50000*128
    int2* list_he = (int2*)(cluster_feat + (size_t)N_P * D_IN); // 5000*CAP_HE  (8B-aligned: float bytes %8==0)
    int2* list_p  = list_he + (size_t)N_HE * CAP_HE;            // 50000*CAP_P
    int* cnt_he  = (int*)(list_p + (size_t)N_P * CAP_P);        // 5000
    int* cnt_p   = cnt_he + N_HE;                               // 50000
    int* ovf_he_cnt = cnt_p + N_P;                              // 1
    int* ovf_p_cnt  = ovf_he_cnt + 1;                           // 1
    int* ovf_he  = ovf_p_cnt + 1;                               // N_E
    int* ovf_p   = ovf_he + N_E;                                // N_E

    k_zero_int<<<64, 256, 0, stream>>>(cnt_he, (unsigned)(N_HE + N_P + 2));
    k_bucket<<<2048, 256, 0, stream>>>(edge_pid, edge_hid, edge_w, cnt_he, cnt_p,
                                       list_he, list_p, ovf_he, ovf_he_cnt, ovf_p, ovf_p_cnt);
    k_gather_he<<<N_HE, 256, 0, stream>>>(feat, cnt_he, list_he, he_feat);
    k_ovf_he<<<256, 256, 0, stream>>>(feat, edge_w, edge_pid, edge_hid, ovf_he, ovf_he_cnt, he_feat);
    k_attn<<<2048, 256, 0, stream>>>(he_feat, Wh1, bh1, Wh2, bh2, Wfuse);
    k_gather_clu<<<N_P, 128, 0, stream>>>(he_feat, cnt_p, list_p, cluster_feat);
    k_ovf_clu<<<256, 256, 0, stream>>>(he_feat, edge_w, edge_pid, edge_hid, ovf_p, ovf_p_cnt, cluster_feat);
    k_final<<<N_P / PT, 256, 0, stream>>>(feat, cluster_feat, Wself, bself, Wclu, bclu,
                                          Wf1, bf1_, Wf2, bf2_, Wf3, bf3_, out);
}

// Round 8
// 627.577 us; speedup vs baseline: 1.6763x; 1.0736x over previous
//
#include <hip/hip_runtime.h>

#define N_P 50000
#define N_HE 5000
#define N_E 800000
#define D_IN 128
#define D_HID 256
#define N_HEADS 4
#define HEAD_DIM 64
#define PT 8        // proteins per block in k_final
#define CAP_HE 320  // bucket capacity per hyperedge (mean 160)
#define CAP_P  64   // bucket capacity per protein   (mean 16)

// ---------------- zero the counters (ints) ----------------
__global__ void k_zero_int(int* __restrict__ p, unsigned n) {
    unsigned i = blockIdx.x * blockDim.x + threadIdx.x;
    unsigned stride = gridDim.x * blockDim.x;
    for (; i < n; i += stride) p[i] = 0;
}

// ---------------- bucket edges; lists store packed (index, weight) ----------------
__global__ void k_bucket(
    const int* __restrict__ edge_pid, const int* __restrict__ edge_hid,
    const float* __restrict__ edge_w,
    int* __restrict__ cnt_he, int* __restrict__ cnt_p,
    int2* __restrict__ list_he, int2* __restrict__ list_p,
    int* __restrict__ ovf_he, int* __restrict__ ovf_he_cnt,
    int* __restrict__ ovf_p,  int* __restrict__ ovf_p_cnt) {
    unsigned e = blockIdx.x * blockDim.x + threadIdx.x;
    unsigned stride = gridDim.x * blockDim.x;
    for (; e < N_E; e += stride) {
        int h = edge_hid[e], p = edge_pid[e];
        int wbits = __float_as_int(edge_w[e]);
        int pos = atomicAdd(cnt_he + h, 1);
        if (pos < CAP_HE) list_he[h * CAP_HE + pos] = make_int2(p, wbits);  // (pid, w)
        else              ovf_he[atomicAdd(ovf_he_cnt, 1)] = (int)e;
        int pp = atomicAdd(cnt_p + p, 1);
        if (pp < CAP_P)   list_p[p * CAP_P + pp] = make_int2(h, wbits);     // (hid, w)
        else              ovf_p[atomicAdd(ovf_p_cnt, 1)] = (int)e;
    }
}

// ---------------- fused Stage 1+2: gather he_feat row, attention, weighted write ----------------
__global__ void k_he(
    const float* __restrict__ feat,
    const int* __restrict__ cnt_he, const int2* __restrict__ list_he,
    const int* __restrict__ ovf_he, const int* __restrict__ ovf_he_cnt,
    const float* __restrict__ edge_w,
    const int* __restrict__ edge_pid, const int* __restrict__ edge_hid,
    const float* __restrict__ Wh1, const float* __restrict__ bh1,
    const float* __restrict__ Wh2, const float* __restrict__ bh2,
    const float* __restrict__ Wfuse,
    float* __restrict__ he_weighted) {
    __shared__ float hef[D_IN];
    __shared__ float tmp[D_IN];
    __shared__ float attnv[N_HEADS];
    __shared__ float heattn;
    int h = blockIdx.x;                 // 5000 blocks
    int t = threadIdx.x;                // 256 threads
    int half = t >> 7, d = t & 127;

    // --- gather: hef[d] = sum_e feat[pid][d] * w ---
    int n = cnt_he[h]; if (n > CAP_HE) n = CAP_HE;
    const int2* lst = list_he + (size_t)h * CAP_HE;
    float acc = 0.f;
    #pragma unroll 4
    for (int k = half; k < n; k += 2) {
        int2 pr = lst[k];               // broadcast read
        acc += feat[(unsigned)pr.x * D_IN + d] * __int_as_float(pr.y);
    }
    int oc = *ovf_he_cnt;               // normally 0
    for (int k = half; k < oc; k += 2) {
        int e = ovf_he[k];
        if (edge_hid[e] == h)
            acc += feat[(unsigned)edge_pid[e] * D_IN + d] * edge_w[e];
    }
    if (half == 1) tmp[d] = acc;
    __syncthreads();
    if (half == 0) hef[d] = acc + tmp[d];
    __syncthreads();

    // --- attention: wave = head ---
    int head = t >> 6, k = t & 63;
    float s = bh1[head * HEAD_DIM + k];
    for (int dd = 0; dd < D_IN; ++dd)
        s += hef[dd] * Wh1[(head * D_IN + dd) * HEAD_DIM + k];
    s = fmaxf(s, 0.f);                          // relu
    float val = s * Wh2[head * HEAD_DIM + k];
    for (int off = 32; off; off >>= 1) val += __shfl_down(val, off);
    if (k == 0) {
        float x = val + bh2[head];
        attnv[head] = 1.f / (1.f + expf(-x));   // sigmoid
    }
    __syncthreads();
    if (t == 0) {
        float ha = 0.f;
        #pragma unroll
        for (int hh = 0; hh < N_HEADS; ++hh) ha += attnv[hh] * Wfuse[hh];
        heattn = ha;
    }
    __syncthreads();
    if (t < D_IN) he_weighted[h * D_IN + t] = hef[t] * heattn;
}

// ---------------- Stage 3 gather: cluster_feat[p] = sum he_w[hid]*w ----------------
__global__ void k_gather_clu(
    const float* __restrict__ he_weighted,
    const int* __restrict__ cnt_p, const int2* __restrict__ list_p,
    const int* __restrict__ ovf_p, const int* __restrict__ ovf_p_cnt,
    const float* __restrict__ edge_w,
    const int* __restrict__ edge_pid, const int* __restrict__ edge_hid,
    float* __restrict__ cluster_feat) {
    int p = blockIdx.x;                 // 50000 blocks
    int n = cnt_p[p]; if (n > CAP_P) n = CAP_P;
    const int2* lst = list_p + (size_t)p * CAP_P;
    int d = threadIdx.x;                // 128 threads
    float acc = 0.f;
    #pragma unroll 4
    for (int k = 0; k < n; ++k) {
        int2 pr = lst[k];               // broadcast read
        acc += he_weighted[(unsigned)pr.x * D_IN + d] * __int_as_float(pr.y);
    }
    int oc = *ovf_p_cnt;                // normally 0
    for (int k = 0; k < oc; ++k) {
        int e = ovf_p[k];
        if (edge_pid[e] == p)
            acc += he_weighted[(unsigned)edge_hid[e] * D_IN + d] * edge_w[e];
    }
    cluster_feat[p * D_IN + d] = acc;
}

// ---------------- Stage 4: register-blocked MLP, [p][d] LDS layout ----------------
// Activation reads in matvec phases are thread-uniform broadcasts (conflict-free)
// and 16B-aligned (float4 -> ds_read_b128). Writes are consecutive-j (2-way = free).
__global__ void k_final(
    const float* __restrict__ feat, const float* __restrict__ cluster_feat,
    const float* __restrict__ Wself, const float* __restrict__ bself,
    const float* __restrict__ Wclu, const float* __restrict__ bclu,
    const float* __restrict__ Wf1, const float* __restrict__ bf1,
    const float* __restrict__ Wf2, const float* __restrict__ bf2,
    const float* __restrict__ Wf3, const float* __restrict__ bf3,
    float* __restrict__ out) {
    __shared__ float featL[PT][D_IN];        // 4 KB
    __shared__ float cluL [PT][D_IN];        // 4 KB
    __shared__ float catL [PT][2 * D_IN];    // 8 KB
    __shared__ float h1L  [PT][D_HID];       // 8 KB
    __shared__ float h2L  [PT][D_HID / 2];   // 4 KB
    __shared__ float fw   [PT * 2];
    int t = threadIdx.x;

    for (int pb = blockIdx.x; pb < N_P / PT; pb += gridDim.x) {
        int p0 = pb * PT;
        const float* fbase = feat + (size_t)p0 * D_IN;
        const float* cbase = cluster_feat + (size_t)p0 * D_IN;

        // flat copy (layout matches global)
        #pragma unroll
        for (int k = 0; k < (PT * D_IN) / 256; ++k) {
            int i = t + k * 256;
            ((float*)featL)[i] = fbase[i];
            ((float*)cluL)[i]  = cbase[i];
        }
        __syncthreads();

        {   // cat = [feat@Wself+bself | clu@Wclu+bclu]
            int j = t;
            const float* W;  const float (*act)[D_IN];  float b;  int jj;
            if (j < D_IN) { W = Wself; b = bself[j];        act = featL; jj = j; }
            else          { W = Wclu;  b = bclu[j - D_IN];  act = cluL;  jj = j - D_IN; }
            float acc[PT];
            #pragma unroll
            for (int p = 0; p < PT; ++p) acc[p] = b;
            for (int d0 = 0; d0 < D_IN; d0 += 8) {
                float w[8];
                #pragma unroll
                for (int q = 0; q < 8; ++q) w[q] = W[(d0 + q) * D_IN + jj];
                #pragma unroll
                for (int p = 0; p < PT; ++p) {
                    float4 a0 = *(const float4*)&act[p][d0];
                    float4 a1 = *(const float4*)&act[p][d0 + 4];
                    acc[p] += a0.x * w[0] + a0.y * w[1] + a0.z * w[2] + a0.w * w[3]
                            + a1.x * w[4] + a1.y * w[5] + a1.z * w[6] + a1.w * w[7];
                }
            }
            #pragma unroll
            for (int p = 0; p < PT; ++p) catL[p][j] = acc[p];
        }
        __syncthreads();

        {   // h1 = relu(cat @ Wf1 + bf1)
            int j = t;
            float acc[PT];
            float b = bf1[j];
            #pragma unroll
            for (int p = 0; p < PT; ++p) acc[p] = b;
            for (int d0 = 0; d0 < 2 * D_IN; d0 += 8) {
                float w[8];
                #pragma unroll
                for (int q = 0; q < 8; ++q) w[q] = Wf1[(d0 + q) * D_HID + j];
                #pragma unroll
                for (int p = 0; p < PT; ++p) {
                    float4 a0 = *(const float4*)&catL[p][d0];
                    float4 a1 = *(const float4*)&catL[p][d0 + 4];
                    acc[p] += a0.x * w[0] + a0.y * w[1] + a0.z * w[2] + a0.w * w[3]
                            + a1.x * w[4] + a1.y * w[5] + a1.z * w[6] + a1.w * w[7];
                }
            }
            #pragma unroll
            for (int p = 0; p < PT; ++p) h1L[p][j] = fmaxf(acc[p], 0.f);
        }
        __syncthreads();

        {   // h2 = relu(h1 @ Wf2 + bf2), 4 proteins per thread
            int j = t & 127, ph = t >> 7;            // ph uniform per wave
            float acc[4];
            float b = bf2[j];
            #pragma unroll
            for (int q = 0; q < 4; ++q) acc[q] = b;
            for (int d0 = 0; d0 < D_HID; d0 += 8) {
                float w[8];
                #pragma unroll
                for (int q = 0; q < 8; ++q) w[q] = Wf2[(d0 + q) * (D_HID / 2) + j];
                #pragma unroll
                for (int r = 0; r < 4; ++r) {
                    int p = ph * 4 + r;
                    float4 a0 = *(const float4*)&h1L[p][d0];
                    float4 a1 = *(const float4*)&h1L[p][d0 + 4];
                    acc[r] += a0.x * w[0] + a0.y * w[1] + a0.z * w[2] + a0.w * w[3]
                            + a1.x * w[4] + a1.y * w[5] + a1.z * w[6] + a1.w * w[7];
                }
            }
            #pragma unroll
            for (int q = 0; q < 4; ++q) h2L[ph * 4 + q][j] = fmaxf(acc[q], 0.f);
        }
        __syncthreads();

        {   // logits + softmax (32 threads per protein)
            int p = t >> 5, k = t & 31;
            float s0 = 0.f, s1 = 0.f;
            for (int d = k; d < D_HID / 2; d += 32) {
                float h = h2L[p][d];
                s0 += h * Wf3[d * 2 + 0];
                s1 += h * Wf3[d * 2 + 1];
            }
            for (int off = 16; off; off >>= 1) {
                s0 += __shfl_down(s0, off, 32);
                s1 += __shfl_down(s1, off, 32);
            }
            if (k == 0) {
                float l0 = s0 + bf3[0], l1 = s1 + bf3[1];
                float m = fmaxf(l0, l1);
                float e0 = expf(l0 - m), e1 = expf(l1 - m);
                float inv = 1.f / (e0 + e1);
                fw[p * 2 + 0] = e0 * inv;
                fw[p * 2 + 1] = e1 * inv;
            }
        }
        __syncthreads();

        // fuse + residual + relu + store (flat, coalesced)
        #pragma unroll
        for (int k = 0; k < (PT * D_IN) / 256; ++k) {
            int i = t + k * 256;
            int p = i >> 7, j = i & 127;
            float fused = catL[p][j] * fw[p * 2 + 0] +
                          catL[p][D_IN + j] * fw[p * 2 + 1];
            float v = fused + featL[p][j];
            out[(size_t)p0 * D_IN + i] = fmaxf(v, 0.f);
        }
        __syncthreads();
    }
}

extern "C" void kernel_launch(void* const* d_in, const int* in_sizes, int n_in,
                              void* d_out, int out_size, void* d_ws, size_t ws_size,
                              hipStream_t stream) {
    (void)in_sizes; (void)n_in; (void)out_size; (void)ws_size;
    const float* feat   = (const float*)d_in[0];
    const float* edge_w = (const float*)d_in[1];
    const float* Wself  = (const float*)d_in[2];
    const float* bself  = (const float*)d_in[3];
    const float* Wclu   = (const float*)d_in[4];
    const float* bclu   = (const float*)d_in[5];
    const float* Wh1    = (const float*)d_in[6];
    const float* bh1    = (const float*)d_in[7];
    const float* Wh2    = (const float*)d_in[8];
    const float* bh2    = (const float*)d_in[9];
    const float* Wfuse  = (const float*)d_in[10];
    const float* Wf1    = (const float*)d_in[11];
    const float* bf1_   = (const float*)d_in[12];
    const float* Wf2    = (const float*)d_in[13];
    const float* bf2_   = (const float*)d_in[14];
    const float* Wf3    = (const float*)d_in[15];
    const float* bf3_   = (const float*)d_in[16];
    const int* edge_pid = (const int*)d_in[17];
    const int* edge_hid = (const int*)d_in[18];
    float* out = (float*)d_out;

    // ---- workspace carve-up (floats, then int2 lists, then ints) ----
    float* he_feat      = (float*)d_ws;                         // 5000*128 (weighted in place)
    float* cluster_feat = he_feat + (size_t)N_HE * D_IN;        // 50000*128
    int2* list_he = (int2*)(cluster_feat + (size_t)N_P * D_IN); // 5000*CAP_HE
    int2* list_p  = list_he + (size_t)N_HE * CAP_HE;            // 50000*CAP_P
    int* cnt_he  = (int*)(list_p + (size_t)N_P * CAP_P);        // 5000
    int* cnt_p   = cnt_he + N_HE;                               // 50000
    int* ovf_he_cnt = cnt_p + N_P;                              // 1
    int* ovf_p_cnt  = ovf_he_cnt + 1;                           // 1
    int* ovf_he  = ovf_p_cnt + 1;                               // N_E
    int* ovf_p   = ovf_he + N_E;                                // N_E

    k_zero_int<<<64, 256, 0, stream>>>(cnt_he, (unsigned)(N_HE + N_P + 2));
    k_bucket<<<2048, 256, 0, stream>>>(edge_pid, edge_hid, edge_w, cnt_he, cnt_p,
                                       list_he, list_p, ovf_he, ovf_he_cnt, ovf_p, ovf_p_cnt);
    k_he<<<N_HE, 256, 0, stream>>>(feat, cnt_he, list_he, ovf_he, ovf_he_cnt,
                                   edge_w, edge_pid, edge_hid,
                                   Wh1, bh1, Wh2, bh2, Wfuse, he_feat);
    k_gather_clu<<<N_P, 128, 0, stream>>>(he_feat, cnt_p, list_p, ovf_p, ovf_p_cnt,
                                          edge_w, edge_pid, edge_hid, cluster_feat);
    k_final<<<N_P / PT, 256, 0, stream>>>(feat, cluster_feat, Wself, bself, Wclu, bclu,
                                          Wf1, bf1_, Wf2, bf2_, Wf3, bf3_, out);
}

// Round 10
// 560.651 us; speedup vs baseline: 1.8764x; 1.1194x over previous
//
#include <hip/hip_runtime.h>

#define N_P 50000
#define N_HE 5000
#define N_E 800000
#define D_IN 128
#define D_HID 256
#define N_HEADS 4
#define HEAD_DIM 64
#define MP 16       // proteins per block in k_final (MFMA M-tile)
#define FS 136      // LDS stride (shorts) for K=128 rows
#define CS 264      // LDS stride (shorts) for K=256 rows
#define HS 132      // LDS stride (floats) for h2
#define CAP_HE 320  // bucket capacity per hyperedge (mean 160)
#define CAP_P  64   // bucket capacity per protein   (mean 16)

typedef __attribute__((ext_vector_type(8))) short short8;
typedef __attribute__((ext_vector_type(4))) float f32x4;

__device__ __forceinline__ short f2bs(float x) {   // fp32 -> bf16 bits (RNE)
    union { float f; unsigned u; } v; v.f = x;
    unsigned r = (v.u + 0x7FFFu + ((v.u >> 16) & 1u)) >> 16;
    return (short)r;
}
__device__ __forceinline__ float bs2f(short s) {
    union { unsigned u; float f; } v; v.u = ((unsigned)(unsigned short)s) << 16;
    return v.f;
}

// ---------------- zero the counters (ints) ----------------
__global__ void k_zero_int(int* __restrict__ p, unsigned n) {
    unsigned i = blockIdx.x * blockDim.x + threadIdx.x;
    unsigned stride = gridDim.x * blockDim.x;
    for (; i < n; i += stride) p[i] = 0;
}

// ---------------- weight prep: fp32 -> split bf16 (hi+lo), transposed WT[n][k] ----------------
__global__ void k_prep(
    const float* __restrict__ Wself, const float* __restrict__ Wclu,
    const float* __restrict__ Wf1,   const float* __restrict__ Wf2,
    short* __restrict__ WselfT_hi, short* __restrict__ WselfT_lo,
    short* __restrict__ WcluT_hi,  short* __restrict__ WcluT_lo,
    short* __restrict__ Wf1T_hi,   short* __restrict__ Wf1T_lo,
    short* __restrict__ Wf2T_hi,   short* __restrict__ Wf2T_lo) {
    unsigned i = blockIdx.x * 256u + threadIdx.x;   // 512*256 = 131072 exact
    float v; short *hi, *lo; unsigned idx;
    if (i < 16384u) {                  // WselfT[j][d], j,d<128
        unsigned j = i >> 7, d = i & 127u;
        v = Wself[d * 128 + j]; hi = WselfT_hi; lo = WselfT_lo; idx = i;
    } else if (i < 32768u) {
        unsigned ii = i - 16384u, j = ii >> 7, d = ii & 127u;
        v = Wclu[d * 128 + j]; hi = WcluT_hi; lo = WcluT_lo; idx = ii;
    } else if (i < 98304u) {           // Wf1T[j][d], j<256,d<256
        unsigned ii = i - 32768u, j = ii >> 8, d = ii & 255u;
        v = Wf1[d * 256 + j]; hi = Wf1T_hi; lo = Wf1T_lo; idx = ii;
    } else {                           // Wf2T[j][d], j<128,d<256
        unsigned ii = i - 98304u, j = ii >> 8, d = ii & 255u;
        v = Wf2[d * 128 + j]; hi = Wf2T_hi; lo = Wf2T_lo; idx = ii;
    }
    short h = f2bs(v);
    hi[idx] = h;
    lo[idx] = f2bs(v - bs2f(h));
}

// ---------------- bucket edges; lists store packed (index, weight) ----------------
__global__ void k_bucket(
    const int* __restrict__ edge_pid, const int* __restrict__ edge_hid,
    const float* __restrict__ edge_w,
    int* __restrict__ cnt_he, int* __restrict__ cnt_p,
    int2* __restrict__ list_he, int2* __restrict__ list_p,
    int* __restrict__ ovf_he, int* __restrict__ ovf_he_cnt,
    int* __restrict__ ovf_p,  int* __restrict__ ovf_p_cnt) {
    unsigned e = blockIdx.x * blockDim.x + threadIdx.x;
    unsigned stride = gridDim.x * blockDim.x;
    for (; e < N_E; e += stride) {
        int h = edge_hid[e], p = edge_pid[e];
        int wbits = __float_as_int(edge_w[e]);
        int pos = atomicAdd(cnt_he + h, 1);
        if (pos < CAP_HE) list_he[h * CAP_HE + pos] = make_int2(p, wbits);
        else              ovf_he[atomicAdd(ovf_he_cnt, 1)] = (int)e;
        int pp = atomicAdd(cnt_p + p, 1);
        if (pp < CAP_P)   list_p[p * CAP_P + pp] = make_int2(h, wbits);
        else              ovf_p[atomicAdd(ovf_p_cnt, 1)] = (int)e;
    }
}

// ---------------- fused Stage 1+2: gather he_feat row, attention, weighted write ----------------
__global__ void k_he(
    const float* __restrict__ feat,
    const int* __restrict__ cnt_he, const int2* __restrict__ list_he,
    const int* __restrict__ ovf_he, const int* __restrict__ ovf_he_cnt,
    const float* __restrict__ edge_w,
    const int* __restrict__ edge_pid, const int* __restrict__ edge_hid,
    const float* __restrict__ Wh1, const float* __restrict__ bh1,
    const float* __restrict__ Wh2, const float* __restrict__ bh2,
    const float* __restrict__ Wfuse,
    float* __restrict__ he_weighted) {
    __shared__ float hef[D_IN];
    __shared__ float tmp[D_IN];
    __shared__ float attnv[N_HEADS];
    __shared__ float heattn;
    int h = blockIdx.x;
    int t = threadIdx.x;
    int half = t >> 7, d = t & 127;

    int n = cnt_he[h]; if (n > CAP_HE) n = CAP_HE;
    const int2* lst = list_he + (size_t)h * CAP_HE;
    float acc = 0.f;
    #pragma unroll 4
    for (int k = half; k < n; k += 2) {
        int2 pr = lst[k];
        acc += feat[(unsigned)pr.x * D_IN + d] * __int_as_float(pr.y);
    }
    int oc = *ovf_he_cnt;
    for (int k = half; k < oc; k += 2) {
        int e = ovf_he[k];
        if (edge_hid[e] == h)
            acc += feat[(unsigned)edge_pid[e] * D_IN + d] * edge_w[e];
    }
    if (half == 1) tmp[d] = acc;
    __syncthreads();
    if (half == 0) hef[d] = acc + tmp[d];
    __syncthreads();

    int head = t >> 6, k = t & 63;
    float s = bh1[head * HEAD_DIM + k];
    for (int dd = 0; dd < D_IN; ++dd)
        s += hef[dd] * Wh1[(head * D_IN + dd) * HEAD_DIM + k];
    s = fmaxf(s, 0.f);
    float val = s * Wh2[head * HEAD_DIM + k];
    for (int off = 32; off; off >>= 1) val += __shfl_down(val, off);
    if (k == 0) {
        float x = val + bh2[head];
        attnv[head] = 1.f / (1.f + expf(-x));
    }
    __syncthreads();
    if (t == 0) {
        float ha = 0.f;
        #pragma unroll
        for (int hh = 0; hh < N_HEADS; ++hh) ha += attnv[hh] * Wfuse[hh];
        heattn = ha;
    }
    __syncthreads();
    if (t < D_IN) he_weighted[h * D_IN + t] = hef[t] * heattn;
}

// ---------------- Stage 3 gather: cluster_feat[p] = sum he_w[hid]*w ----------------
__global__ void k_gather_clu(
    const float* __restrict__ he_weighted,
    const int* __restrict__ cnt_p, const int2* __restrict__ list_p,
    const int* __restrict__ ovf_p, const int* __restrict__ ovf_p_cnt,
    const float* __restrict__ edge_w,
    const int* __restrict__ edge_pid, const int* __restrict__ edge_hid,
    float* __restrict__ cluster_feat) {
    int p = blockIdx.x;
    int n = cnt_p[p]; if (n > CAP_P) n = CAP_P;
    const int2* lst = list_p + (size_t)p * CAP_P;
    int d = threadIdx.x;
    float acc = 0.f;
    #pragma unroll 4
    for (int k = 0; k < n; ++k) {
        int2 pr = lst[k];
        acc += he_weighted[(unsigned)pr.x * D_IN + d] * __int_as_float(pr.y);
    }
    int oc = *ovf_p_cnt;
    for (int k = 0; k < oc; ++k) {
        int e = ovf_p[k];
        if (edge_pid[e] == p)
            acc += he_weighted[(unsigned)edge_hid[e] * D_IN + d] * edge_w[e];
    }
    cluster_feat[p * D_IN + d] = acc;
}

// ---------------- Stage 4: split-bf16 MFMA MLP, 16 proteins/block ----------------
// Every operand is hi+lo bf16 (together ~16 mantissa bits); acc += ah*bh + al*bh + ah*bl
// in fp32 gives near-fp32 GEMMs. A-frag: A[m=lane&15][k=quad*8+j]; C/D: col=lane&15,
// row=quad*4+reg (m89/m120-verified, dtype-independent).
__global__ void k_final(
    const float* __restrict__ feat, const float* __restrict__ cluster_feat,
    const short* __restrict__ WselfT_hi, const short* __restrict__ WselfT_lo, const float* __restrict__ bself,
    const short* __restrict__ WcluT_hi,  const short* __restrict__ WcluT_lo,  const float* __restrict__ bclu,
    const short* __restrict__ Wf1T_hi,   const short* __restrict__ Wf1T_lo,   const float* __restrict__ bf1,
    const short* __restrict__ Wf2T_hi,   const short* __restrict__ Wf2T_lo,   const float* __restrict__ bf2,
    const float* __restrict__ Wf3,       const float* __restrict__ bf3,
    float* __restrict__ out) {
    __shared__ __align__(16) short featB_hi[MP * FS];
    __shared__ __align__(16) short featB_lo[MP * FS];
    __shared__ __align__(16) short cluB_hi [MP * FS];
    __shared__ __align__(16) short cluB_lo [MP * FS];
    __shared__ __align__(16) short catB_hi [MP * CS];
    __shared__ __align__(16) short catB_lo [MP * CS];
    __shared__ __align__(16) short h1B_hi  [MP * CS];
    __shared__ __align__(16) short h1B_lo  [MP * CS];
    __shared__ float h2F[MP * HS];
    __shared__ float fw[MP * 2];
    int t = threadIdx.x;
    int p0 = blockIdx.x * MP;          // 3125 blocks exactly

    // ---- Stage A: load feat/cluster, split into hi+lo bf16 ----
    {
        int p = t >> 4, j = (t & 15) * 8;
        const float* fr = feat + (size_t)(p0 + p) * D_IN + j;
        const float* cr = cluster_feat + (size_t)(p0 + p) * D_IN + j;
        float4 f0 = *(const float4*)fr, f1 = *(const float4*)(fr + 4);
        float4 c0 = *(const float4*)cr, c1 = *(const float4*)(cr + 4);
        float fv[8] = {f0.x, f0.y, f0.z, f0.w, f1.x, f1.y, f1.z, f1.w};
        float cv[8] = {c0.x, c0.y, c0.z, c0.w, c1.x, c1.y, c1.z, c1.w};
        short8 fh, fl, ch, cl;
        #pragma unroll
        for (int q = 0; q < 8; ++q) {
            short h = f2bs(fv[q]); fh[q] = h; fl[q] = f2bs(fv[q] - bs2f(h));
            short h2 = f2bs(cv[q]); ch[q] = h2; cl[q] = f2bs(cv[q] - bs2f(h2));
        }
        *(short8*)&featB_hi[p * FS + j] = fh;
        *(short8*)&featB_lo[p * FS + j] = fl;
        *(short8*)&cluB_hi [p * FS + j] = ch;
        *(short8*)&cluB_lo [p * FS + j] = cl;
    }
    __syncthreads();

    int wv = t >> 6, lane = t & 63, col = lane & 15, q = lane >> 4;

    // ---- Stage B: cat = [feat@Wself+bself | clu@Wclu+bclu]  (K=128) ----
    {
        const short* aHi = (wv < 2) ? featB_hi : cluB_hi;
        const short* aLo = (wv < 2) ? featB_lo : cluB_lo;
        const short* bHi = (wv < 2) ? WselfT_hi : WcluT_hi;
        const short* bLo = (wv < 2) ? WselfT_lo : WcluT_lo;
        const float* bias = (wv < 2) ? bself : bclu;
        int nb = (wv & 1) * 64;
        f32x4 acc[4];
        #pragma unroll
        for (int i = 0; i < 4; ++i) acc[i] = (f32x4){0.f, 0.f, 0.f, 0.f};
        #pragma unroll
        for (int ks = 0; ks < 4; ++ks) {
            int kb = ks * 32 + q * 8;
            short8 ah = *(const short8*)&aHi[col * FS + kb];
            short8 al = *(const short8*)&aLo[col * FS + kb];
            #pragma unroll
            for (int i = 0; i < 4; ++i) {
                int n = nb + i * 16 + col;
                short8 bh = *(const short8*)&bHi[n * 128 + kb];
                short8 bl = *(const short8*)&bLo[n * 128 + kb];
                acc[i] = __builtin_amdgcn_mfma_f32_16x16x32_bf16(ah, bh, acc[i], 0, 0, 0);
                acc[i] = __builtin_amdgcn_mfma_f32_16x16x32_bf16(al, bh, acc[i], 0, 0, 0);
                acc[i] = __builtin_amdgcn_mfma_f32_16x16x32_bf16(ah, bl, acc[i], 0, 0, 0);
            }
        }
        int cofs = (wv < 2) ? 0 : 128;
        #pragma unroll
        for (int i = 0; i < 4; ++i) {
            int n = nb + i * 16 + col;
            float bv = bias[n];
            #pragma unroll
            for (int r = 0; r < 4; ++r) {
                float v = acc[i][r] + bv;
                short h = f2bs(v);
                catB_hi[(q * 4 + r) * CS + cofs + n] = h;
                catB_lo[(q * 4 + r) * CS + cofs + n] = f2bs(v - bs2f(h));
            }
        }
    }
    __syncthreads();

    // ---- Stage C: h1 = relu(cat @ Wf1 + bf1)  (K=256, N=256) ----
    {
        f32x4 acc[4];
        #pragma unroll
        for (int i = 0; i < 4; ++i) acc[i] = (f32x4){0.f, 0.f, 0.f, 0.f};
        #pragma unroll
        for (int ks = 0; ks < 8; ++ks) {
            int kb = ks * 32 + q * 8;
            short8 ah = *(const short8*)&catB_hi[col * CS + kb];
            short8 al = *(const short8*)&catB_lo[col * CS + kb];
            #pragma unroll
            for (int i = 0; i < 4; ++i) {
                int n = wv * 64 + i * 16 + col;
                short8 bh = *(const short8*)&Wf1T_hi[n * 256 + kb];
                short8 bl = *(const short8*)&Wf1T_lo[n * 256 + kb];
                acc[i] = __builtin_amdgcn_mfma_f32_16x16x32_bf16(ah, bh, acc[i], 0, 0, 0);
                acc[i] = __builtin_amdgcn_mfma_f32_16x16x32_bf16(al, bh, acc[i], 0, 0, 0);
                acc[i] = __builtin_amdgcn_mfma_f32_16x16x32_bf16(ah, bl, acc[i], 0, 0, 0);
            }
        }
        #pragma unroll
        for (int i = 0; i < 4; ++i) {
            int n = wv * 64 + i * 16 + col;
            float bv = bf1[n];
            #pragma unroll
            for (int r = 0; r < 4; ++r) {
                float v = fmaxf(acc[i][r] + bv, 0.f);
                short h = f2bs(v);
                h1B_hi[(q * 4 + r) * CS + n] = h;
                h1B_lo[(q * 4 + r) * CS + n] = f2bs(v - bs2f(h));
            }
        }
    }
    __syncthreads();

    // ---- Stage D: h2 = relu(h1 @ Wf2 + bf2)  (K=256, N=128), store fp32 ----
    {
        f32x4 acc[2];
        #pragma unroll
        for (int i = 0; i < 2; ++i) acc[i] = (f32x4){0.f, 0.f, 0.f, 0.f};
        #pragma unroll
        for (int ks = 0; ks < 8; ++ks) {
            int kb = ks * 32 + q * 8;
            short8 ah = *(const short8*)&h1B_hi[col * CS + kb];
            short8 al = *(const short8*)&h1B_lo[col * CS + kb];
            #pragma unroll
            for (int i = 0; i < 2; ++i) {
                int n = wv * 32 + i * 16 + col;
                short8 bh = *(const short8*)&Wf2T_hi[n * 256 + kb];
                short8 bl = *(const short8*)&Wf2T_lo[n * 256 + kb];
                acc[i] = __builtin_amdgcn_mfma_f32_16x16x32_bf16(ah, bh, acc[i], 0, 0, 0);
                acc[i] = __builtin_amdgcn_mfma_f32_16x16x32_bf16(al, bh, acc[i], 0, 0, 0);
                acc[i] = __builtin_amdgcn_mfma_f32_16x16x32_bf16(ah, bl, acc[i], 0, 0, 0);
            }
        }
        #pragma unroll
        for (int i = 0; i < 2; ++i) {
            int n = wv * 32 + i * 16 + col;
            float bv = bf2[n];
            #pragma unroll
            for (int r = 0; r < 4; ++r)
                h2F[(q * 4 + r) * HS + n] = fmaxf(acc[i][r] + bv, 0.f);
        }
    }
    __syncthreads();

    // ---- Stage E: logits + softmax (16 threads per protein, fp32) ----
    {
        int p = t >> 4, kk = t & 15;
        float s0 = 0.f, s1 = 0.f;
        for (int d = kk; d < D_HID / 2; d += 16) {
            float h = h2F[p * HS + d];
            s0 += h * Wf3[d * 2 + 0];
            s1 += h * Wf3[d * 2 + 1];
        }
        #pragma unroll
        for (int off = 8; off; off >>= 1) {
            s0 += __shfl_down(s0, off, 16);
            s1 += __shfl_down(s1, off, 16);
        }
        if (kk == 0) {
            float l0 = s0 + bf3[0], l1 = s1 + bf3[1];
            float m = fmaxf(l0, l1);
            float e0 = expf(l0 - m), e1 = expf(l1 - m);
            float inv = 1.f / (e0 + e1);
            fw[p * 2 + 0] = e0 * inv;
            fw[p * 2 + 1] = e1 * inv;
        }
    }
    __syncthreads();

    // ---- Stage F: fuse + residual + relu + store (hi+lo reconstruct) ----
    {
        int p = t >> 4, j = (t & 15) * 8;
        float f0 = fw[p * 2 + 0], f1 = fw[p * 2 + 1];
        float o[8];
        #pragma unroll
        for (int qq = 0; qq < 8; ++qq) {
            int jj = j + qq;
            float self_f = bs2f(catB_hi[p * CS + jj]) + bs2f(catB_lo[p * CS + jj]);
            float clu_f  = bs2f(catB_hi[p * CS + 128 + jj]) + bs2f(catB_lo[p * CS + 128 + jj]);
            float fe     = bs2f(featB_hi[p * FS + jj]) + bs2f(featB_lo[p * FS + jj]);
            o[qq] = fmaxf(self_f * f0 + clu_f * f1 + fe, 0.f);
        }
        float* ob = out + (size_t)(p0 + p) * D_IN + j;
        *(float4*)ob = make_float4(o[0], o[1], o[2], o[3]);
        *(float4*)(ob + 4) = make_float4(o[4], o[5], o[6], o[7]);
    }
}

extern "C" void kernel_launch(void* const* d_in, const int* in_sizes, int n_in,
                              void* d_out, int out_size, void* d_ws, size_t ws_size,
                              hipStream_t stream) {
    (void)in_sizes; (void)n_in; (void)out_size; (void)ws_size;
    const float* feat   = (const float*)d_in[0];
    const float* edge_w = (const float*)d_in[1];
    const float* Wself  = (const float*)d_in[2];
    const float* bself  = (const float*)d_in[3];
    const float* Wclu   = (const float*)d_in[4];
    const float* bclu   = (const float*)d_in[5];
    const float* Wh1    = (const float*)d_in[6];
    const float* bh1    = (const float*)d_in[7];
    const float* Wh2    = (const float*)d_in[8];
    const float* bh2    = (const float*)d_in[9];
    const float* Wfuse  = (const float*)d_in[10];
    const float* Wf1    = (const float*)d_in[11];
    const float* bf1_   = (const float*)d_in[12];
    const float* Wf2    = (const float*)d_in[13];
    const float* bf2_   = (const float*)d_in[14];
    const float* Wf3    = (const float*)d_in[15];
    const float* bf3_   = (const float*)d_in[16];
    const int* edge_pid = (const int*)d_in[17];
    const int* edge_hid = (const int*)d_in[18];
    float* out = (float*)d_out;

    // ---- workspace carve-up ----
    float* he_feat      = (float*)d_ws;                         // 5000*128
    float* cluster_feat = he_feat + (size_t)N_HE * D_IN;        // 50000*128
    int2* list_he = (int2*)(cluster_feat + (size_t)N_P * D_IN); // 5000*CAP_HE
    int2* list_p  = list_he + (size_t)N_HE * CAP_HE;            // 50000*CAP_P
    int* cnt_he  = (int*)(list_p + (size_t)N_P * CAP_P);        // 5000
    int* cnt_p   = cnt_he + N_HE;                               // 50000
    int* ovf_he_cnt = cnt_p + N_P;                              // 1
    int* ovf_p_cnt  = ovf_he_cnt + 1;                           // 1
    int* ovf_he  = ovf_p_cnt + 1;                               // N_E
    int* ovf_p   = ovf_he + N_E;                                // N_E
    short* WselfT_hi = (short*)(ovf_p + N_E);                   // 128*128 each
    short* WselfT_lo = WselfT_hi + 128 * 128;
    short* WcluT_hi  = WselfT_lo + 128 * 128;
    short* WcluT_lo  = WcluT_hi + 128 * 128;
    short* Wf1T_hi   = WcluT_lo + 128 * 128;                    // 256*256 each
    short* Wf1T_lo   = Wf1T_hi + 256 * 256;
    short* Wf2T_hi   = Wf1T_lo + 256 * 256;                     // 128*256 each
    short* Wf2T_lo   = Wf2T_hi + 128 * 256;

    k_prep<<<512, 256, 0, stream>>>(Wself, Wclu, Wf1, Wf2,
                                    WselfT_hi, WselfT_lo, WcluT_hi, WcluT_lo,
                                    Wf1T_hi, Wf1T_lo, Wf2T_hi, Wf2T_lo);
    k_zero_int<<<64, 256, 0, stream>>>(cnt_he, (unsigned)(N_HE + N_P + 2));
    k_bucket<<<2048, 256, 0, stream>>>(edge_pid, edge_hid, edge_w, cnt_he, cnt_p,
                                       list_he, list_p, ovf_he, ovf_he_cnt, ovf_p, ovf_p_cnt);
    k_he<<<N_HE, 256, 0, stream>>>(feat, cnt_he, list_he, ovf_he, ovf_he_cnt,
                                   edge_w, edge_pid, edge_hid,
                                   Wh1, bh1, Wh2, bh2, Wfuse, he_feat);
    k_gather_clu<<<N_P, 128, 0, stream>>>(he_feat, cnt_p, list_p, ovf_p, ovf_p_cnt,
                                          edge_w, edge_pid, edge_hid, cluster_feat);
    k_final<<<N_P / MP, 256, 0, stream>>>(feat, cluster_feat,
                                          WselfT_hi, WselfT_lo, bself,
                                          WcluT_hi, WcluT_lo, bclu,
                                          Wf1T_hi, Wf1T_lo, bf1_,
                                          Wf2T_hi, Wf2T_lo, bf2_,
                                          Wf3, bf3_, out);
}

// Round 11
// 525.721 us; speedup vs baseline: 2.0011x; 1.0664x over previous
//
#include <hip/hip_runtime.h>

#define N_P 50000
#define N_HE 5000
#define N_E 800000
#define D_IN 128
#define D_HID 256
#define N_HEADS 4
#define HEAD_DIM 64
#define MP 16       // proteins per block in k_final (MFMA M-tile)
#define FS 136      // LDS stride (shorts) for K=128 rows
#define CS 264      // LDS stride (shorts) for K=256 rows
#define HS 132      // LDS stride (floats) for h2
#define CAP_HE 320  // bucket capacity per hyperedge (mean 160)
#define CAP_P  64   // bucket capacity per protein   (mean 16)

typedef __attribute__((ext_vector_type(8))) short short8;
typedef __attribute__((ext_vector_type(4))) float f32x4;

__device__ __forceinline__ short f2bs(float x) {   // fp32 -> bf16 bits (RNE)
    union { float f; unsigned u; } v; v.f = x;
    unsigned r = (v.u + 0x7FFFu + ((v.u >> 16) & 1u)) >> 16;
    return (short)r;
}
__device__ __forceinline__ float bs2f(short s) {
    union { unsigned u; float f; } v; v.u = ((unsigned)(unsigned short)s) << 16;
    return v.f;
}

// ---------------- zero the counters (ints) ----------------
__global__ void k_zero_int(int* __restrict__ p, unsigned n) {
    unsigned i = blockIdx.x * blockDim.x + threadIdx.x;
    unsigned stride = gridDim.x * blockDim.x;
    for (; i < n; i += stride) p[i] = 0;
}

// ---------------- weight prep: fp32 -> split bf16 (hi+lo), transposed WT[n][k] ----------------
__global__ void k_prep(
    const float* __restrict__ Wself, const float* __restrict__ Wclu,
    const float* __restrict__ Wf1,   const float* __restrict__ Wf2,
    short* __restrict__ WselfT_hi, short* __restrict__ WselfT_lo,
    short* __restrict__ WcluT_hi,  short* __restrict__ WcluT_lo,
    short* __restrict__ Wf1T_hi,   short* __restrict__ Wf1T_lo,
    short* __restrict__ Wf2T_hi,   short* __restrict__ Wf2T_lo) {
    unsigned i = blockIdx.x * 256u + threadIdx.x;   // 512*256 = 131072 exact
    float v; short *hi, *lo; unsigned idx;
    if (i < 16384u) {                  // WselfT[j][d], j,d<128
        unsigned j = i >> 7, d = i & 127u;
        v = Wself[d * 128 + j]; hi = WselfT_hi; lo = WselfT_lo; idx = i;
    } else if (i < 32768u) {
        unsigned ii = i - 16384u, j = ii >> 7, d = ii & 127u;
        v = Wclu[d * 128 + j]; hi = WcluT_hi; lo = WcluT_lo; idx = ii;
    } else if (i < 98304u) {           // Wf1T[j][d], j<256,d<256
        unsigned ii = i - 32768u, j = ii >> 8, d = ii & 255u;
        v = Wf1[d * 256 + j]; hi = Wf1T_hi; lo = Wf1T_lo; idx = ii;
    } else {                           // Wf2T[j][d], j<128,d<256
        unsigned ii = i - 98304u, j = ii >> 8, d = ii & 255u;
        v = Wf2[d * 128 + j]; hi = Wf2T_hi; lo = Wf2T_lo; idx = ii;
    }
    short h = f2bs(v);
    hi[idx] = h;
    lo[idx] = f2bs(v - bs2f(h));
}

// ---------------- bucket edges; lists store packed (index, weight) ----------------
__global__ void k_bucket(
    const int* __restrict__ edge_pid, const int* __restrict__ edge_hid,
    const float* __restrict__ edge_w,
    int* __restrict__ cnt_he, int* __restrict__ cnt_p,
    int2* __restrict__ list_he, int2* __restrict__ list_p,
    int* __restrict__ ovf_he, int* __restrict__ ovf_he_cnt,
    int* __restrict__ ovf_p,  int* __restrict__ ovf_p_cnt) {
    unsigned e = blockIdx.x * blockDim.x + threadIdx.x;
    unsigned stride = gridDim.x * blockDim.x;
    for (; e < N_E; e += stride) {
        int h = edge_hid[e], p = edge_pid[e];
        int wbits = __float_as_int(edge_w[e]);
        int pos = atomicAdd(cnt_he + h, 1);
        if (pos < CAP_HE) list_he[h * CAP_HE + pos] = make_int2(p, wbits);
        else              ovf_he[atomicAdd(ovf_he_cnt, 1)] = (int)e;
        int pp = atomicAdd(cnt_p + p, 1);
        if (pp < CAP_P)   list_p[p * CAP_P + pp] = make_int2(h, wbits);
        else              ovf_p[atomicAdd(ovf_p_cnt, 1)] = (int)e;
    }
}

// ---------------- fused Stage 1+2: gather he_feat row, attention, weighted write ----------------
__global__ void k_he(
    const float* __restrict__ feat,
    const int* __restrict__ cnt_he, const int2* __restrict__ list_he,
    const int* __restrict__ ovf_he, const int* __restrict__ ovf_he_cnt,
    const float* __restrict__ edge_w,
    const int* __restrict__ edge_pid, const int* __restrict__ edge_hid,
    const float* __restrict__ Wh1, const float* __restrict__ bh1,
    const float* __restrict__ Wh2, const float* __restrict__ bh2,
    const float* __restrict__ Wfuse,
    float* __restrict__ he_weighted) {
    __shared__ float hef[D_IN];
    __shared__ float tmp[D_IN];
    __shared__ float attnv[N_HEADS];
    __shared__ float heattn;
    int h = blockIdx.x;
    int t = threadIdx.x;
    int half = t >> 7, d = t & 127;

    int n = cnt_he[h]; if (n > CAP_HE) n = CAP_HE;
    const int2* lst = list_he + (size_t)h * CAP_HE;
    float acc = 0.f;
    #pragma unroll 4
    for (int k = half; k < n; k += 2) {
        int2 pr = lst[k];
        acc += feat[(unsigned)pr.x * D_IN + d] * __int_as_float(pr.y);
    }
    int oc = *ovf_he_cnt;
    for (int k = half; k < oc; k += 2) {
        int e = ovf_he[k];
        if (edge_hid[e] == h)
            acc += feat[(unsigned)edge_pid[e] * D_IN + d] * edge_w[e];
    }
    if (half == 1) tmp[d] = acc;
    __syncthreads();
    if (half == 0) hef[d] = acc + tmp[d];
    __syncthreads();

    int head = t >> 6, k = t & 63;
    float s = bh1[head * HEAD_DIM + k];
    for (int dd = 0; dd < D_IN; ++dd)
        s += hef[dd] * Wh1[(head * D_IN + dd) * HEAD_DIM + k];
    s = fmaxf(s, 0.f);
    float val = s * Wh2[head * HEAD_DIM + k];
    for (int off = 32; off; off >>= 1) val += __shfl_down(val, off);
    if (k == 0) {
        float x = val + bh2[head];
        attnv[head] = 1.f / (1.f + expf(-x));
    }
    __syncthreads();
    if (t == 0) {
        float ha = 0.f;
        #pragma unroll
        for (int hh = 0; hh < N_HEADS; ++hh) ha += attnv[hh] * Wfuse[hh];
        heattn = ha;
    }
    __syncthreads();
    if (t < D_IN) he_weighted[h * D_IN + t] = hef[t] * heattn;
}

// ---------------- Stage 3 gather: cluster_feat[p] = sum he_w[hid]*w ----------------
__global__ void k_gather_clu(
    const float* __restrict__ he_weighted,
    const int* __restrict__ cnt_p, const int2* __restrict__ list_p,
    const int* __restrict__ ovf_p, const int* __restrict__ ovf_p_cnt,
    const float* __restrict__ edge_w,
    const int* __restrict__ edge_pid, const int* __restrict__ edge_hid,
    float* __restrict__ cluster_feat) {
    int p = blockIdx.x;
    int n = cnt_p[p]; if (n > CAP_P) n = CAP_P;
    const int2* lst = list_p + (size_t)p * CAP_P;
    int d = threadIdx.x;
    float acc = 0.f;
    #pragma unroll 4
    for (int k = 0; k < n; ++k) {
        int2 pr = lst[k];
        acc += he_weighted[(unsigned)pr.x * D_IN + d] * __int_as_float(pr.y);
    }
    int oc = *ovf_p_cnt;
    for (int k = 0; k < oc; ++k) {
        int e = ovf_p[k];
        if (edge_pid[e] == p)
            acc += he_weighted[(unsigned)edge_hid[e] * D_IN + d] * edge_w[e];
    }
    cluster_feat[p * D_IN + d] = acc;
}

// ---------------- Stage 4: split-bf16 MFMA MLP with pipelined B-loads ----------------
// acc += ah*bh + al*bh + ah*bl (fp32 accum) ~= fp32 GEMM. B-fragments are
// explicitly double-buffered in registers so global L2 latency overlaps MFMA.
// cluB (dead after stage B) aliases h2F (born stage D) -> 51.3 KB LDS, 3 blocks/CU.
__global__ void k_final(
    const float* __restrict__ feat, const float* __restrict__ cluster_feat,
    const short* __restrict__ WselfT_hi, const short* __restrict__ WselfT_lo, const float* __restrict__ bself,
    const short* __restrict__ WcluT_hi,  const short* __restrict__ WcluT_lo,  const float* __restrict__ bclu,
    const short* __restrict__ Wf1T_hi,   const short* __restrict__ Wf1T_lo,   const float* __restrict__ bf1,
    const short* __restrict__ Wf2T_hi,   const short* __restrict__ Wf2T_lo,   const float* __restrict__ bf2,
    const float* __restrict__ Wf3,       const float* __restrict__ bf3,
    float* __restrict__ out) {
    __shared__ __align__(16) short featB_hi[MP * FS];
    __shared__ __align__(16) short featB_lo[MP * FS];
    __shared__ __align__(16) unsigned char ubuf[MP * FS * 2 * sizeof(short)]; // cluB hi+lo | h2F
    __shared__ __align__(16) short catB_hi [MP * CS];
    __shared__ __align__(16) short catB_lo [MP * CS];
    __shared__ __align__(16) short h1B_hi  [MP * CS];
    __shared__ __align__(16) short h1B_lo  [MP * CS];
    __shared__ float fw[MP * 2];
    short* cluB_hi = (short*)ubuf;                  // MP*FS shorts
    short* cluB_lo = (short*)ubuf + MP * FS;        // MP*FS shorts
    float* h2F     = (float*)ubuf;                  // MP*HS floats (8448 <= 8704 B)
    int t = threadIdx.x;
    int p0 = blockIdx.x * MP;          // 3125 blocks exactly

    // ---- Stage A: load feat/cluster, split into hi+lo bf16 ----
    {
        int p = t >> 4, j = (t & 15) * 8;
        const float* fr = feat + (size_t)(p0 + p) * D_IN + j;
        const float* cr = cluster_feat + (size_t)(p0 + p) * D_IN + j;
        float4 f0 = *(const float4*)fr, f1 = *(const float4*)(fr + 4);
        float4 c0 = *(const float4*)cr, c1 = *(const float4*)(cr + 4);
        float fv[8] = {f0.x, f0.y, f0.z, f0.w, f1.x, f1.y, f1.z, f1.w};
        float cv[8] = {c0.x, c0.y, c0.z, c0.w, c1.x, c1.y, c1.z, c1.w};
        short8 fh, fl, ch, cl;
        #pragma unroll
        for (int q = 0; q < 8; ++q) {
            short h = f2bs(fv[q]); fh[q] = h; fl[q] = f2bs(fv[q] - bs2f(h));
            short h2 = f2bs(cv[q]); ch[q] = h2; cl[q] = f2bs(cv[q] - bs2f(h2));
        }
        *(short8*)&featB_hi[p * FS + j] = fh;
        *(short8*)&featB_lo[p * FS + j] = fl;
        *(short8*)&cluB_hi [p * FS + j] = ch;
        *(short8*)&cluB_lo [p * FS + j] = cl;
    }
    __syncthreads();

    int wv = t >> 6, lane = t & 63, col = lane & 15, q = lane >> 4;

    // ---- Stage B: cat = [feat@Wself+bself | clu@Wclu+bclu]  (K=128) ----
    {
        const short* aHi = (wv < 2) ? featB_hi : cluB_hi;
        const short* aLo = (wv < 2) ? featB_lo : cluB_lo;
        const short* bHi = (wv < 2) ? WselfT_hi : WcluT_hi;
        const short* bLo = (wv < 2) ? WselfT_lo : WcluT_lo;
        const float* bias = (wv < 2) ? bself : bclu;
        int nb = (wv & 1) * 64;
        f32x4 acc[4];
        short8 bh[4], bl[4];
        #pragma unroll
        for (int i = 0; i < 4; ++i) {
            acc[i] = (f32x4){0.f, 0.f, 0.f, 0.f};
            int n = nb + i * 16 + col;
            bh[i] = *(const short8*)&bHi[n * 128 + q * 8];
            bl[i] = *(const short8*)&bLo[n * 128 + q * 8];
        }
        #pragma unroll
        for (int ks = 0; ks < 4; ++ks) {
            int kb = ks * 32 + q * 8;
            short8 nh[4], nl[4];
            if (ks < 3) {
                #pragma unroll
                for (int i = 0; i < 4; ++i) {
                    int n = nb + i * 16 + col;
                    nh[i] = *(const short8*)&bHi[n * 128 + kb + 32];
                    nl[i] = *(const short8*)&bLo[n * 128 + kb + 32];
                }
            }
            short8 ah = *(const short8*)&aHi[col * FS + kb];
            short8 al = *(const short8*)&aLo[col * FS + kb];
            #pragma unroll
            for (int i = 0; i < 4; ++i) {
                acc[i] = __builtin_amdgcn_mfma_f32_16x16x32_bf16(ah, bh[i], acc[i], 0, 0, 0);
                acc[i] = __builtin_amdgcn_mfma_f32_16x16x32_bf16(al, bh[i], acc[i], 0, 0, 0);
                acc[i] = __builtin_amdgcn_mfma_f32_16x16x32_bf16(ah, bl[i], acc[i], 0, 0, 0);
            }
            if (ks < 3) {
                #pragma unroll
                for (int i = 0; i < 4; ++i) { bh[i] = nh[i]; bl[i] = nl[i]; }
            }
        }
        int cofs = (wv < 2) ? 0 : 128;
        #pragma unroll
        for (int i = 0; i < 4; ++i) {
            int n = nb + i * 16 + col;
            float bv = bias[n];
            #pragma unroll
            for (int r = 0; r < 4; ++r) {
                float v = acc[i][r] + bv;
                short h = f2bs(v);
                catB_hi[(q * 4 + r) * CS + cofs + n] = h;
                catB_lo[(q * 4 + r) * CS + cofs + n] = f2bs(v - bs2f(h));
            }
        }
    }
    __syncthreads();

    // ---- Stage C: h1 = relu(cat @ Wf1 + bf1)  (K=256, N=256) ----
    {
        f32x4 acc[4];
        short8 bh[4], bl[4];
        #pragma unroll
        for (int i = 0; i < 4; ++i) {
            acc[i] = (f32x4){0.f, 0.f, 0.f, 0.f};
            int n = wv * 64 + i * 16 + col;
            bh[i] = *(const short8*)&Wf1T_hi[n * 256 + q * 8];
            bl[i] = *(const short8*)&Wf1T_lo[n * 256 + q * 8];
        }
        #pragma unroll
        for (int ks = 0; ks < 8; ++ks) {
            int kb = ks * 32 + q * 8;
            short8 nh[4], nl[4];
            if (ks < 7) {
                #pragma unroll
                for (int i = 0; i < 4; ++i) {
                    int n = wv * 64 + i * 16 + col;
                    nh[i] = *(const short8*)&Wf1T_hi[n * 256 + kb + 32];
                    nl[i] = *(const short8*)&Wf1T_lo[n * 256 + kb + 32];
                }
            }
            short8 ah = *(const short8*)&catB_hi[col * CS + kb];
            short8 al = *(const short8*)&catB_lo[col * CS + kb];
            #pragma unroll
            for (int i = 0; i < 4; ++i) {
                acc[i] = __builtin_amdgcn_mfma_f32_16x16x32_bf16(ah, bh[i], acc[i], 0, 0, 0);
                acc[i] = __builtin_amdgcn_mfma_f32_16x16x32_bf16(al, bh[i], acc[i], 0, 0, 0);
                acc[i] = __builtin_amdgcn_mfma_f32_16x16x32_bf16(ah, bl[i], acc[i], 0, 0, 0);
            }
            if (ks < 7) {
                #pragma unroll
                for (int i = 0; i < 4; ++i) { bh[i] = nh[i]; bl[i] = nl[i]; }
            }
        }
        #pragma unroll
        for (int i = 0; i < 4; ++i) {
            int n = wv * 64 + i * 16 + col;
            float bv = bf1[n];
            #pragma unroll
            for (int r = 0; r < 4; ++r) {
                float v = fmaxf(acc[i][r] + bv, 0.f);
                short h = f2bs(v);
                h1B_hi[(q * 4 + r) * CS + n] = h;
                h1B_lo[(q * 4 + r) * CS + n] = f2bs(v - bs2f(h));
            }
        }
    }
    __syncthreads();

    // ---- Stage D: h2 = relu(h1 @ Wf2 + bf2)  (K=256, N=128), store fp32 ----
    {
        f32x4 acc[2];
        short8 bh[2], bl[2];
        #pragma unroll
        for (int i = 0; i < 2; ++i) {
            acc[i] = (f32x4){0.f, 0.f, 0.f, 0.f};
            int n = wv * 32 + i * 16 + col;
            bh[i] = *(const short8*)&Wf2T_hi[n * 256 + q * 8];
            bl[i] = *(const short8*)&Wf2T_lo[n * 256 + q * 8];
        }
        #pragma unroll
        for (int ks = 0; ks < 8; ++ks) {
            int kb = ks * 32 + q * 8;
            short8 nh[2], nl[2];
            if (ks < 7) {
                #pragma unroll
                for (int i = 0; i < 2; ++i) {
                    int n = wv * 32 + i * 16 + col;
                    nh[i] = *(const short8*)&Wf2T_hi[n * 256 + kb + 32];
                    nl[i] = *(const short8*)&Wf2T_lo[n * 256 + kb + 32];
                }
            }
            short8 ah = *(const short8*)&h1B_hi[col * CS + kb];
            short8 al = *(const short8*)&h1B_lo[col * CS + kb];
            #pragma unroll
            for (int i = 0; i < 2; ++i) {
                acc[i] = __builtin_amdgcn_mfma_f32_16x16x32_bf16(ah, bh[i], acc[i], 0, 0, 0);
                acc[i] = __builtin_amdgcn_mfma_f32_16x16x32_bf16(al, bh[i], acc[i], 0, 0, 0);
                acc[i] = __builtin_amdgcn_mfma_f32_16x16x32_bf16(ah, bl[i], acc[i], 0, 0, 0);
            }
            if (ks < 7) {
                #pragma unroll
                for (int i = 0; i < 2; ++i) { bh[i] = nh[i]; bl[i] = nl[i]; }
            }
        }
        #pragma unroll
        for (int i = 0; i < 2; ++i) {
            int n = wv * 32 + i * 16 + col;
            float bv = bf2[n];
            #pragma unroll
            for (int r = 0; r < 4; ++r)
                h2F[(q * 4 + r) * HS + n] = fmaxf(acc[i][r] + bv, 0.f);
        }
    }
    __syncthreads();

    // ---- Stage E: logits + softmax (16 threads per protein, fp32) ----
    {
        int p = t >> 4, kk = t & 15;
        float s0 = 0.f, s1 = 0.f;
        for (int d = kk; d < D_HID / 2; d += 16) {
            float h = h2F[p * HS + d];
            s0 += h * Wf3[d * 2 + 0];
            s1 += h * Wf3[d * 2 + 1];
        }
        #pragma unroll
        for (int off = 8; off; off >>= 1) {
            s0 += __shfl_down(s0, off, 16);
            s1 += __shfl_down(s1, off, 16);
        }
        if (kk == 0) {
            float l0 = s0 + bf3[0], l1 = s1 + bf3[1];
            float m = fmaxf(l0, l1);
            float e0 = expf(l0 - m), e1 = expf(l1 - m);
            float inv = 1.f / (e0 + e1);
            fw[p * 2 + 0] = e0 * inv;
            fw[p * 2 + 1] = e1 * inv;
        }
    }
    __syncthreads();

    // ---- Stage F: fuse + residual + relu + store (hi+lo reconstruct) ----
    {
        int p = t >> 4, j = (t & 15) * 8;
        float f0 = fw[p * 2 + 0], f1 = fw[p * 2 + 1];
        float o[8];
        #pragma unroll
        for (int qq = 0; qq < 8; ++qq) {
            int jj = j + qq;
            float self_f = bs2f(catB_hi[p * CS + jj]) + bs2f(catB_lo[p * CS + jj]);
            float clu_f  = bs2f(catB_hi[p * CS + 128 + jj]) + bs2f(catB_lo[p * CS + 128 + jj]);
            float fe     = bs2f(featB_hi[p * FS + jj]) + bs2f(featB_lo[p * FS + jj]);
            o[qq] = fmaxf(self_f * f0 + clu_f * f1 + fe, 0.f);
        }
        float* ob = out + (size_t)(p0 + p) * D_IN + j;
        *(float4*)ob = make_float4(o[0], o[1], o[2], o[3]);
        *(float4*)(ob + 4) = make_float4(o[4], o[5], o[6], o[7]);
    }
}

extern "C" void kernel_launch(void* const* d_in, const int* in_sizes, int n_in,
                              void* d_out, int out_size, void* d_ws, size_t ws_size,
                              hipStream_t stream) {
    (void)in_sizes; (void)n_in; (void)out_size; (void)ws_size;
    const float* feat   = (const float*)d_in[0];
    const float* edge_w = (const float*)d_in[1];
    const float* Wself  = (const float*)d_in[2];
    const float* bself  = (const float*)d_in[3];
    const float* Wclu   = (const float*)d_in[4];
    const float* bclu   = (const float*)d_in[5];
    const float* Wh1    = (const float*)d_in[6];
    const float* bh1    = (const float*)d_in[7];
    const float* Wh2    = (const float*)d_in[8];
    const float* bh2    = (const float*)d_in[9];
    const float* Wfuse  = (const float*)d_in[10];
    const float* Wf1    = (const float*)d_in[11];
    const float* bf1_   = (const float*)d_in[12];
    const float* Wf2    = (const float*)d_in[13];
    const float* bf2_   = (const float*)d_in[14];
    const float* Wf3    = (const float*)d_in[15];
    const float* bf3_   = (const float*)d_in[16];
    const int* edge_pid = (const int*)d_in[17];
    const int* edge_hid = (const int*)d_in[18];
    float* out = (float*)d_out;

    // ---- workspace carve-up ----
    float* he_feat      = (float*)d_ws;                         // 5000*128
    float* cluster_feat = he_feat + (size_t)N_HE * D_IN;        // 50000*128
    int2* list_he = (int2*)(cluster_feat + (size_t)N_P * D_IN); // 5000*CAP_HE
    int2* list_p  = list_he + (size_t)N_HE * CAP_HE;            // 50000*CAP_P
    int* cnt_he  = (int*)(list_p + (size_t)N_P * CAP_P);        // 5000
    int* cnt_p   = cnt_he + N_HE;                               // 50000
    int* ovf_he_cnt = cnt_p + N_P;                              // 1
    int* ovf_p_cnt  = ovf_he_cnt + 1;                           // 1
    int* ovf_he  = ovf_p_cnt + 1;                               // N_E
    int* ovf_p   = ovf_he + N_E;                                // N_E
    short* WselfT_hi = (short*)(ovf_p + N_E);                   // 128*128 each
    short* WselfT_lo = WselfT_hi + 128 * 128;
    short* WcluT_hi  = WselfT_lo + 128 * 128;
    short* WcluT_lo  = WcluT_hi + 128 * 128;
    short* Wf1T_hi   = WcluT_lo + 128 * 128;                    // 256*256 each
    short* Wf1T_lo   = Wf1T_hi + 256 * 256;
    short* Wf2T_hi   = Wf1T_lo + 256 * 256;                     // 128*256 each
    short* Wf2T_lo   = Wf2T_hi + 128 * 256;

    k_prep<<<512, 256, 0, stream>>>(Wself, Wclu, Wf1, Wf2,
                                    WselfT_hi, WselfT_lo, WcluT_hi, WcluT_lo,
                                    Wf1T_hi, Wf1T_lo, Wf2T_hi, Wf2T_lo);
    k_zero_int<<<64, 256, 0, stream>>>(cnt_he, (unsigned)(N_HE + N_P + 2));
    k_bucket<<<2048, 256, 0, stream>>>(edge_pid, edge_hid, edge_w, cnt_he, cnt_p,
                                       list_he, list_p, ovf_he, ovf_he_cnt, ovf_p, ovf_p_cnt);
    k_he<<<N_HE, 256, 0, stream>>>(feat, cnt_he, list_he, ovf_he, ovf_he_cnt,
                                   edge_w, edge_pid, edge_hid,
                                   Wh1, bh1, Wh2, bh2, Wfuse, he_feat);
    k_gather_clu<<<N_P, 128, 0, stream>>>(he_feat, cnt_p, list_p, ovf_p, ovf_p_cnt,
                                          edge_w, edge_pid, edge_hid, cluster_feat);
    k_final<<<N_P / MP, 256, 0, stream>>>(feat, cluster_feat,
                                          WselfT_hi, WselfT_lo, bself,
                                          WcluT_hi, WcluT_lo, bclu,
                                          Wf1T_hi, Wf1T_lo, bf1_,
                                          Wf2T_hi, Wf2T_lo, bf2_,
                                          Wf3, bf3_, out);
}

// Round 12
// 480.462 us; speedup vs baseline: 2.1896x; 1.0942x over previous
//
#include <hip/hip_runtime.h>

#define N_P 50000
#define N_HE 5000
#define N_E 800000
#define D_IN 128
#define D_HID 256
#define N_HEADS 4
#define HEAD_DIM 64
#define CAP_HE 320
#define CAP_P  64
#define NTILE_TOT 3125   // 50000 / 16
#define NCHUNK 782       // ceil(3125 / 4) chunks of 64 rows
#define CS2 264          // LDS stride (shorts) for h1

typedef __attribute__((ext_vector_type(8))) short short8;
typedef __attribute__((ext_vector_type(4))) float f32x4;

__device__ __forceinline__ short f2bs(float x) {   // fp32 -> bf16 bits (RNE)
    union { float f; unsigned u; } v; v.f = x;
    unsigned r = (v.u + 0x7FFFu + ((v.u >> 16) & 1u)) >> 16;
    return (short)r;
}
__device__ __forceinline__ float bs2f(short s) {
    union { unsigned u; float f; } v; v.u = ((unsigned)(unsigned short)s) << 16;
    return v.f;
}

__global__ void k_zero_int(int* __restrict__ p, unsigned n) {
    unsigned i = blockIdx.x * blockDim.x + threadIdx.x;
    unsigned stride = gridDim.x * blockDim.x;
    for (; i < n; i += stride) p[i] = 0;
}

// ---------------- weight prep: fp32 -> split bf16 (hi+lo), transposed WT[n][k] ----------------
__global__ void k_prep(
    const float* __restrict__ Wself, const float* __restrict__ Wclu,
    const float* __restrict__ Wf1,   const float* __restrict__ Wf2,
    short* __restrict__ WselfT_hi, short* __restrict__ WselfT_lo,
    short* __restrict__ WcluT_hi,  short* __restrict__ WcluT_lo,
    short* __restrict__ Wf1T_hi,   short* __restrict__ Wf1T_lo,
    short* __restrict__ Wf2T_hi,   short* __restrict__ Wf2T_lo) {
    unsigned i = blockIdx.x * 256u + threadIdx.x;   // 512*256 = 131072 exact
    float v; short *hi, *lo; unsigned idx;
    if (i < 16384u) {
        unsigned j = i >> 7, d = i & 127u;
        v = Wself[d * 128 + j]; hi = WselfT_hi; lo = WselfT_lo; idx = i;
    } else if (i < 32768u) {
        unsigned ii = i - 16384u, j = ii >> 7, d = ii & 127u;
        v = Wclu[d * 128 + j]; hi = WcluT_hi; lo = WcluT_lo; idx = ii;
    } else if (i < 98304u) {
        unsigned ii = i - 32768u, j = ii >> 8, d = ii & 255u;
        v = Wf1[d * 256 + j]; hi = Wf1T_hi; lo = Wf1T_lo; idx = ii;
    } else {
        unsigned ii = i - 98304u, j = ii >> 8, d = ii & 255u;
        v = Wf2[d * 128 + j]; hi = Wf2T_hi; lo = Wf2T_lo; idx = ii;
    }
    short h = f2bs(v);
    hi[idx] = h;
    lo[idx] = f2bs(v - bs2f(h));
}

// ---------------- bucket edges; lists store packed (index, weight) ----------------
__global__ void k_bucket(
    const int* __restrict__ edge_pid, const int* __restrict__ edge_hid,
    const float* __restrict__ edge_w,
    int* __restrict__ cnt_he, int* __restrict__ cnt_p,
    int2* __restrict__ list_he, int2* __restrict__ list_p,
    int* __restrict__ ovf_he, int* __restrict__ ovf_he_cnt,
    int* __restrict__ ovf_p,  int* __restrict__ ovf_p_cnt) {
    unsigned e = blockIdx.x * blockDim.x + threadIdx.x;
    unsigned stride = gridDim.x * blockDim.x;
    for (; e < N_E; e += stride) {
        int h = edge_hid[e], p = edge_pid[e];
        int wbits = __float_as_int(edge_w[e]);
        int pos = atomicAdd(cnt_he + h, 1);
        if (pos < CAP_HE) list_he[h * CAP_HE + pos] = make_int2(p, wbits);
        else              ovf_he[atomicAdd(ovf_he_cnt, 1)] = (int)e;
        int pp = atomicAdd(cnt_p + p, 1);
        if (pp < CAP_P)   list_p[p * CAP_P + pp] = make_int2(h, wbits);
        else              ovf_p[atomicAdd(ovf_p_cnt, 1)] = (int)e;
    }
}

// ---------------- fused gather + attention per hyperedge ----------------
__global__ void k_he(
    const float* __restrict__ feat,
    const int* __restrict__ cnt_he, const int2* __restrict__ list_he,
    const int* __restrict__ ovf_he, const int* __restrict__ ovf_he_cnt,
    const float* __restrict__ edge_w,
    const int* __restrict__ edge_pid, const int* __restrict__ edge_hid,
    const float* __restrict__ Wh1, const float* __restrict__ bh1,
    const float* __restrict__ Wh2, const float* __restrict__ bh2,
    const float* __restrict__ Wfuse,
    float* __restrict__ he_weighted) {
    __shared__ float hef[D_IN];
    __shared__ float tmp[D_IN];
    __shared__ float attnv[N_HEADS];
    __shared__ float heattn;
    int h = blockIdx.x;
    int t = threadIdx.x;
    int half = t >> 7, d = t & 127;

    int n = cnt_he[h]; if (n > CAP_HE) n = CAP_HE;
    const int2* lst = list_he + (size_t)h * CAP_HE;
    float acc = 0.f;
    #pragma unroll 4
    for (int k = half; k < n; k += 2) {
        int2 pr = lst[k];
        acc += feat[(unsigned)pr.x * D_IN + d] * __int_as_float(pr.y);
    }
    int oc = *ovf_he_cnt;
    for (int k = half; k < oc; k += 2) {
        int e = ovf_he[k];
        if (edge_hid[e] == h)
            acc += feat[(unsigned)edge_pid[e] * D_IN + d] * edge_w[e];
    }
    if (half == 1) tmp[d] = acc;
    __syncthreads();
    if (half == 0) hef[d] = acc + tmp[d];
    __syncthreads();

    int head = t >> 6, k = t & 63;
    float s = bh1[head * HEAD_DIM + k];
    for (int dd = 0; dd < D_IN; ++dd)
        s += hef[dd] * Wh1[(head * D_IN + dd) * HEAD_DIM + k];
    s = fmaxf(s, 0.f);
    float val = s * Wh2[head * HEAD_DIM + k];
    for (int off = 32; off; off >>= 1) val += __shfl_down(val, off);
    if (k == 0) {
        float x = val + bh2[head];
        attnv[head] = 1.f / (1.f + expf(-x));
    }
    __syncthreads();
    if (t == 0) {
        float ha = 0.f;
        #pragma unroll
        for (int hh = 0; hh < N_HEADS; ++hh) ha += attnv[hh] * Wfuse[hh];
        heattn = ha;
    }
    __syncthreads();
    if (t < D_IN) he_weighted[h * D_IN + t] = hef[t] * heattn;
}

// ---------------- cluster gather ----------------
__global__ void k_gather_clu(
    const float* __restrict__ he_weighted,
    const int* __restrict__ cnt_p, const int2* __restrict__ list_p,
    const int* __restrict__ ovf_p, const int* __restrict__ ovf_p_cnt,
    const float* __restrict__ edge_w,
    const int* __restrict__ edge_pid, const int* __restrict__ edge_hid,
    float* __restrict__ cluster_feat) {
    int p = blockIdx.x;
    int n = cnt_p[p]; if (n > CAP_P) n = CAP_P;
    const int2* lst = list_p + (size_t)p * CAP_P;
    int d = threadIdx.x;
    float acc = 0.f;
    #pragma unroll 4
    for (int k = 0; k < n; ++k) {
        int2 pr = lst[k];
        acc += he_weighted[(unsigned)pr.x * D_IN + d] * __int_as_float(pr.y);
    }
    int oc = *ovf_p_cnt;
    for (int k = 0; k < oc; ++k) {
        int e = ovf_p[k];
        if (edge_pid[e] == p)
            acc += he_weighted[(unsigned)edge_hid[e] * D_IN + d] * edge_w[e];
    }
    cluster_feat[p * D_IN + d] = acc;
}

// ---------------- MLP stage 1: cat = [feat@Wself+b | clu@Wclu+b] -> global hi/lo ----------------
// M=64/block (4 m-tiles). B-fragments (128 VGPRs) loaded once, reused over 4 m-tiles.
__global__ __launch_bounds__(256, 2) void k_mlp1(
    const float* __restrict__ feat, const float* __restrict__ cluster_feat,
    const short* __restrict__ WselfT_hi, const short* __restrict__ WselfT_lo, const float* __restrict__ bself,
    const short* __restrict__ WcluT_hi,  const short* __restrict__ WcluT_lo,  const float* __restrict__ bclu,
    short* __restrict__ catH, short* __restrict__ catL) {
    int t = threadIdx.x;
    int wv = t >> 6, lane = t & 63, col = lane & 15, q = lane >> 4;
    int m0 = blockIdx.x * 64;
    int tiles = NTILE_TOT - blockIdx.x * 4; if (tiles > 4) tiles = 4;
    const float* A = (wv < 2) ? feat : cluster_feat;
    const short* bHi = (wv < 2) ? WselfT_hi : WcluT_hi;
    const short* bLo = (wv < 2) ? WselfT_lo : WcluT_lo;
    const float* bias = (wv < 2) ? bself : bclu;
    int nb = (wv & 1) * 64;
    int cofs = (wv < 2) ? 0 : 128;

    short8 Bh[4][4], Bl[4][4];
    float bv[4];
    #pragma unroll
    for (int i = 0; i < 4; ++i) {
        int n = nb + i * 16 + col;
        bv[i] = bias[n];
        #pragma unroll
        for (int ks = 0; ks < 4; ++ks) {
            int kb = ks * 32 + q * 8;
            Bh[i][ks] = *(const short8*)&bHi[n * 128 + kb];
            Bl[i][ks] = *(const short8*)&bLo[n * 128 + kb];
        }
    }
    for (int mt = 0; mt < tiles; ++mt) {
        int row = m0 + mt * 16 + col;
        f32x4 acc[4];
        #pragma unroll
        for (int i = 0; i < 4; ++i) acc[i] = (f32x4){0.f, 0.f, 0.f, 0.f};
        #pragma unroll
        for (int ks = 0; ks < 4; ++ks) {
            int kb = ks * 32 + q * 8;
            const float* ap = A + (size_t)row * D_IN + kb;
            float4 a0 = *(const float4*)ap, a1 = *(const float4*)(ap + 4);
            float av[8] = {a0.x, a0.y, a0.z, a0.w, a1.x, a1.y, a1.z, a1.w};
            short8 ah, al;
            #pragma unroll
            for (int j = 0; j < 8; ++j) {
                short h = f2bs(av[j]); ah[j] = h; al[j] = f2bs(av[j] - bs2f(h));
            }
            #pragma unroll
            for (int i = 0; i < 4; ++i) {
                acc[i] = __builtin_amdgcn_mfma_f32_16x16x32_bf16(ah, Bh[i][ks], acc[i], 0, 0, 0);
                acc[i] = __builtin_amdgcn_mfma_f32_16x16x32_bf16(al, Bh[i][ks], acc[i], 0, 0, 0);
                acc[i] = __builtin_amdgcn_mfma_f32_16x16x32_bf16(ah, Bl[i][ks], acc[i], 0, 0, 0);
            }
        }
        #pragma unroll
        for (int i = 0; i < 4; ++i) {
            int n = nb + i * 16 + col;
            #pragma unroll
            for (int r = 0; r < 4; ++r) {
                float v = acc[i][r] + bv[i];
                short h = f2bs(v);
                size_t o = (size_t)(m0 + mt * 16 + q * 4 + r) * 256 + cofs + n;
                catH[o] = h;
                catL[o] = f2bs(v - bs2f(h));
            }
        }
    }
}

// ---------------- MLP stages 2+3: h1 (LDS) -> h2 (regs) -> logits/softmax/fuse/out ----------------
__global__ __launch_bounds__(256, 2) void k_mlp23(
    const short* __restrict__ catH, const short* __restrict__ catL,
    const short* __restrict__ Wf1T_hi, const short* __restrict__ Wf1T_lo, const float* __restrict__ bf1,
    const short* __restrict__ Wf2T_hi, const short* __restrict__ Wf2T_lo, const float* __restrict__ bf2,
    const float* __restrict__ Wf3, const float* __restrict__ bf3,
    const float* __restrict__ feat, float* __restrict__ out) {
    __shared__ __align__(16) short h1Hs[64 * CS2];   // 33.8 KB
    __shared__ __align__(16) short h1Ls[64 * CS2];   // 33.8 KB
    __shared__ float fw[64 * 2];
    float* h2F = (float*)h1Hs;       // alias: h1 dead before h2 written (sync-guarded)
    int t = threadIdx.x;
    int wv = t >> 6, lane = t & 63, col = lane & 15, q = lane >> 4;
    int m0 = blockIdx.x * 64;
    int tiles = NTILE_TOT - blockIdx.x * 4; if (tiles > 4) tiles = 4;
    int rows = tiles * 16;

    // ---- stage C: h1 = relu(cat @ Wf1 + bf1); wave n-slice 64, 2 passes of 2 n-subtiles ----
    for (int ih = 0; ih < 2; ++ih) {
        short8 Bh[2][8], Bl[2][8];
        #pragma unroll
        for (int ii = 0; ii < 2; ++ii) {
            int n = wv * 64 + (ih * 2 + ii) * 16 + col;
            #pragma unroll
            for (int ks = 0; ks < 8; ++ks) {
                int kb = ks * 32 + q * 8;
                Bh[ii][ks] = *(const short8*)&Wf1T_hi[n * 256 + kb];
                Bl[ii][ks] = *(const short8*)&Wf1T_lo[n * 256 + kb];
            }
        }
        for (int mt = 0; mt < tiles; ++mt) {
            int row = m0 + mt * 16 + col;
            f32x4 acc[2];
            #pragma unroll
            for (int ii = 0; ii < 2; ++ii) acc[ii] = (f32x4){0.f, 0.f, 0.f, 0.f};
            #pragma unroll
            for (int ks = 0; ks < 8; ++ks) {
                int kb = ks * 32 + q * 8;
                short8 ah = *(const short8*)&catH[(size_t)row * 256 + kb];
                short8 al = *(const short8*)&catL[(size_t)row * 256 + kb];
                #pragma unroll
                for (int ii = 0; ii < 2; ++ii) {
                    acc[ii] = __builtin_amdgcn_mfma_f32_16x16x32_bf16(ah, Bh[ii][ks], acc[ii], 0, 0, 0);
                    acc[ii] = __builtin_amdgcn_mfma_f32_16x16x32_bf16(al, Bh[ii][ks], acc[ii], 0, 0, 0);
                    acc[ii] = __builtin_amdgcn_mfma_f32_16x16x32_bf16(ah, Bl[ii][ks], acc[ii], 0, 0, 0);
                }
            }
            #pragma unroll
            for (int ii = 0; ii < 2; ++ii) {
                int n = wv * 64 + (ih * 2 + ii) * 16 + col;
                float bvv = bf1[n];
                #pragma unroll
                for (int r = 0; r < 4; ++r) {
                    float v = fmaxf(acc[ii][r] + bvv, 0.f);
                    short h = f2bs(v);
                    int rl = mt * 16 + q * 4 + r;
                    h1Hs[rl * CS2 + n] = h;
                    h1Ls[rl * CS2 + n] = f2bs(v - bs2f(h));
                }
            }
        }
    }
    __syncthreads();

    // ---- stage D: h2 = relu(h1 @ Wf2 + bf2); wave n-slice 32; keep results in regs ----
    f32x4 acc2[2][4];
    #pragma unroll
    for (int ii = 0; ii < 2; ++ii)
        #pragma unroll
        for (int mt = 0; mt < 4; ++mt) acc2[ii][mt] = (f32x4){0.f, 0.f, 0.f, 0.f};
    for (int ii = 0; ii < 2; ++ii) {
        short8 Bh2[8], Bl2[8];
        int n = wv * 32 + ii * 16 + col;
        #pragma unroll
        for (int ks = 0; ks < 8; ++ks) {
            int kb = ks * 32 + q * 8;
            Bh2[ks] = *(const short8*)&Wf2T_hi[n * 256 + kb];
            Bl2[ks] = *(const short8*)&Wf2T_lo[n * 256 + kb];
        }
        for (int mt = 0; mt < tiles; ++mt) {
            #pragma unroll
            for (int ks = 0; ks < 8; ++ks) {
                int kb = ks * 32 + q * 8;
                short8 ah = *(const short8*)&h1Hs[(mt * 16 + col) * CS2 + kb];
                short8 al = *(const short8*)&h1Ls[(mt * 16 + col) * CS2 + kb];
                acc2[ii][mt] = __builtin_amdgcn_mfma_f32_16x16x32_bf16(ah, Bh2[ks], acc2[ii][mt], 0, 0, 0);
                acc2[ii][mt] = __builtin_amdgcn_mfma_f32_16x16x32_bf16(al, Bh2[ks], acc2[ii][mt], 0, 0, 0);
                acc2[ii][mt] = __builtin_amdgcn_mfma_f32_16x16x32_bf16(ah, Bl2[ks], acc2[ii][mt], 0, 0, 0);
            }
        }
    }
    __syncthreads();   // all h1 reads complete before h2F overwrites the aliased region

    #pragma unroll
    for (int ii = 0; ii < 2; ++ii) {
        int n = wv * 32 + ii * 16 + col;
        float bvv = bf2[n];
        for (int mt = 0; mt < tiles; ++mt) {
            #pragma unroll
            for (int r = 0; r < 4; ++r)
                h2F[(mt * 16 + q * 4 + r) * 132 + n] = fmaxf(acc2[ii][mt][r] + bvv, 0.f);
        }
    }
    __syncthreads();

    // ---- logits + softmax: 4 threads per protein row ----
    {
        int p = t >> 2, c = t & 3;
        if (p < rows) {
            float s0 = 0.f, s1 = 0.f;
            for (int n = c * 32; n < c * 32 + 32; ++n) {
                float h = h2F[p * 132 + n];
                s0 += h * Wf3[n * 2 + 0];
                s1 += h * Wf3[n * 2 + 1];
            }
            #pragma unroll
            for (int off = 2; off; off >>= 1) {
                s0 += __shfl_down(s0, off, 4);
                s1 += __shfl_down(s1, off, 4);
            }
            if (c == 0) {
                float l0 = s0 + bf3[0], l1 = s1 + bf3[1];
                float m = fmaxf(l0, l1);
                float e0 = expf(l0 - m), e1 = expf(l1 - m);
                float inv = 1.f / (e0 + e1);
                fw[p * 2 + 0] = e0 * inv;
                fw[p * 2 + 1] = e1 * inv;
            }
        }
    }
    __syncthreads();

    // ---- fuse + residual + relu + store ----
    #pragma unroll
    for (int k = 0; k < 4; ++k) {
        int idx = t + k * 256;           // 0..1023 over 64 rows x 16 j-groups
        int rl = idx >> 4;
        int j = (idx & 15) * 8;
        if (rl < rows) {
            size_t ro = (size_t)(m0 + rl);
            short8 sh = *(const short8*)&catH[ro * 256 + j];
            short8 sl = *(const short8*)&catL[ro * 256 + j];
            short8 ch = *(const short8*)&catH[ro * 256 + 128 + j];
            short8 cl = *(const short8*)&catL[ro * 256 + 128 + j];
            const float* fp = feat + ro * D_IN + j;
            float4 f0 = *(const float4*)fp, f1 = *(const float4*)(fp + 4);
            float fe[8] = {f0.x, f0.y, f0.z, f0.w, f1.x, f1.y, f1.z, f1.w};
            float w0 = fw[rl * 2 + 0], w1 = fw[rl * 2 + 1];
            float o[8];
            #pragma unroll
            for (int qq = 0; qq < 8; ++qq) {
                float self_f = bs2f(sh[qq]) + bs2f(sl[qq]);
                float clu_f  = bs2f(ch[qq]) + bs2f(cl[qq]);
                o[qq] = fmaxf(self_f * w0 + clu_f * w1 + fe[qq], 0.f);
            }
            float* ob = out + ro * D_IN + j;
            *(float4*)ob = make_float4(o[0], o[1], o[2], o[3]);
            *(float4*)(ob + 4) = make_float4(o[4], o[5], o[6], o[7]);
        }
    }
}

extern "C" void kernel_launch(void* const* d_in, const int* in_sizes, int n_in,
                              void* d_out, int out_size, void* d_ws, size_t ws_size,
                              hipStream_t stream) {
    (void)in_sizes; (void)n_in; (void)out_size; (void)ws_size;
    const float* feat   = (const float*)d_in[0];
    const float* edge_w = (const float*)d_in[1];
    const float* Wself  = (const float*)d_in[2];
    const float* bself  = (const float*)d_in[3];
    const float* Wclu   = (const float*)d_in[4];
    const float* bclu   = (const float*)d_in[5];
    const float* Wh1    = (const float*)d_in[6];
    const float* bh1    = (const float*)d_in[7];
    const float* Wh2    = (const float*)d_in[8];
    const float* bh2    = (const float*)d_in[9];
    const float* Wfuse  = (const float*)d_in[10];
    const float* Wf1    = (const float*)d_in[11];
    const float* bf1_   = (const float*)d_in[12];
    const float* Wf2    = (const float*)d_in[13];
    const float* bf2_   = (const float*)d_in[14];
    const float* Wf3    = (const float*)d_in[15];
    const float* bf3_   = (const float*)d_in[16];
    const int* edge_pid = (const int*)d_in[17];
    const int* edge_hid = (const int*)d_in[18];
    float* out = (float*)d_out;

    // ---- workspace carve-up ----
    float* he_feat      = (float*)d_ws;                         // 5000*128
    float* cluster_feat = he_feat + (size_t)N_HE * D_IN;        // 50000*128
    int2* list_he = (int2*)(cluster_feat + (size_t)N_P * D_IN); // 5000*CAP_HE
    int2* list_p  = list_he + (size_t)N_HE * CAP_HE;            // 50000*CAP_P
    int* cnt_he  = (int*)(list_p + (size_t)N_P * CAP_P);        // 5000
    int* cnt_p   = cnt_he + N_HE;                               // 50000
    int* ovf_he_cnt = cnt_p + N_P;                              // 1
    int* ovf_p_cnt  = ovf_he_cnt + 1;                           // 1
    int* ovf_he  = ovf_p_cnt + 1;                               // N_E
    int* ovf_p   = ovf_he + N_E;                                // N_E
    short* WselfT_hi = (short*)(ovf_p + N_E);                   // 128*128 each
    short* WselfT_lo = WselfT_hi + 128 * 128;
    short* WcluT_hi  = WselfT_lo + 128 * 128;
    short* WcluT_lo  = WcluT_hi + 128 * 128;
    short* Wf1T_hi   = WcluT_lo + 128 * 128;                    // 256*256 each
    short* Wf1T_lo   = Wf1T_hi + 256 * 256;
    short* Wf2T_hi   = Wf1T_lo + 256 * 256;                     // 128*256 each
    short* Wf2T_lo   = Wf2T_hi + 128 * 256;
    short* catH      = Wf2T_lo + 128 * 256;                     // 50000*256
    short* catL      = catH + (size_t)N_P * 256;                // 50000*256

    k_prep<<<512, 256, 0, stream>>>(Wself, Wclu, Wf1, Wf2,
                                    WselfT_hi, WselfT_lo, WcluT_hi, WcluT_lo,
                                    Wf1T_hi, Wf1T_lo, Wf2T_hi, Wf2T_lo);
    k_zero_int<<<64, 256, 0, stream>>>(cnt_he, (unsigned)(N_HE + N_P + 2));
    k_bucket<<<2048, 256, 0, stream>>>(edge_pid, edge_hid, edge_w, cnt_he, cnt_p,
                                       list_he, list_p, ovf_he, ovf_he_cnt, ovf_p, ovf_p_cnt);
    k_he<<<N_HE, 256, 0, stream>>>(feat, cnt_he, list_he, ovf_he, ovf_he_cnt,
                                   edge_w, edge_pid, edge_hid,
                                   Wh1, bh1, Wh2, bh2, Wfuse, he_feat);
    k_gather_clu<<<N_P, 128, 0, stream>>>(he_feat, cnt_p, list_p, ovf_p, ovf_p_cnt,
                                          edge_w, edge_pid, edge_hid, cluster_feat);
    k_mlp1<<<NCHUNK, 256, 0, stream>>>(feat, cluster_feat,
                                       WselfT_hi, WselfT_lo, bself,
                                       WcluT_hi, WcluT_lo, bclu, catH, catL);
    k_mlp23<<<NCHUNK, 256, 0, stream>>>(catH, catL,
                                        Wf1T_hi, Wf1T_lo, bf1_,
                                        Wf2T_hi, Wf2T_lo, bf2_,
                                        Wf3, bf3_, feat, out);
}